// Round 14
// baseline (386.242 us; speedup 1.0000x reference)
//
#include <hip/hip_runtime.h>

#define N_NODES 50000
#define N_EDGES 800000
#define N_GRAPHS 2000
#define BN_EPS 1e-5f
#define FSHARD 12500  // fill: N_NODES / 4

typedef unsigned short ushort_t;
typedef unsigned int uint_t;
using bf16x8 = __attribute__((ext_vector_type(8))) short;
using f32x4  = __attribute__((ext_vector_type(4))) float;

__device__ inline float bf_lo(uint_t u) { return __uint_as_float(u << 16); }
__device__ inline float bf_hi(uint_t u) { return __uint_as_float(u & 0xffff0000u); }
__device__ inline ushort_t f2bf(float f) {  // round-to-nearest-even
  uint_t u = __float_as_uint(f);
  return (ushort_t)((u + 0x7fffu + ((u >> 16) & 1u)) >> 16);
}
__device__ inline uint_t pack2(float a, float b) {
  return (uint_t)f2bf(a) | ((uint_t)f2bf(b) << 16);
}

// ================================================================ CSR build
__global__ void fill_sharded_kernel(const int* __restrict__ src,
                                    const int* __restrict__ dst,
                                    int* __restrict__ cursor,
                                    ushort_t* __restrict__ col) {
  const int shard = blockIdx.x & 3;
  const int lo = shard * FSHARD, hi = lo + FSHARD;
  const int nb = gridDim.x >> 2, blk = blockIdx.x >> 2;
  for (int e = blk * blockDim.x + threadIdx.x; e < N_EDGES;
       e += nb * blockDim.x) {
    int d = dst[e];
    if (d >= lo && d < hi) {
      int p = atomicAdd(&cursor[d], 1);
      col[p] = (ushort_t)src[e];
    }
  }
}

__global__ void scan_block_kernel(const int* __restrict__ degi,
                                  int* __restrict__ partial,
                                  int* __restrict__ bsum,
                                  float* __restrict__ invdeg) {
  __shared__ int buf[2][256];
  int i = blockIdx.x * 256 + threadIdx.x;
  int v = (i < N_NODES) ? degi[i] : 0;
  buf[0][threadIdx.x] = v;
  __syncthreads();
  int pi = 0;
  for (int off = 1; off < 256; off <<= 1) {
    int nv = buf[pi][threadIdx.x];
    if (threadIdx.x >= off) nv += buf[pi][threadIdx.x - off];
    buf[pi ^ 1][threadIdx.x] = nv;
    pi ^= 1;
    __syncthreads();
  }
  int incl = buf[pi][threadIdx.x];
  if (i < N_NODES) {
    partial[i] = incl - v;
    invdeg[i] = 1.0f / fmaxf((float)v, 1.0f);
  }
  if (threadIdx.x == 255) bsum[blockIdx.x] = incl;
}

__global__ void scan_add_fused_kernel(const int* __restrict__ partial,
                                      const int* __restrict__ bsum,
                                      int* __restrict__ rowptr,
                                      int* __restrict__ cursor, int nb) {
  __shared__ int buf[2][256];
  __shared__ int sx[256];
  int t = threadIdx.x;
  int v = (t < nb) ? bsum[t] : 0;
  buf[0][t] = v;
  __syncthreads();
  int pi = 0;
  for (int off = 1; off < 256; off <<= 1) {
    int nv = buf[pi][t];
    if (t >= off) nv += buf[pi][t - off];
    buf[pi ^ 1][t] = nv;
    pi ^= 1;
    __syncthreads();
  }
  sx[t] = buf[pi][t] - v;
  __syncthreads();
  int add = sx[blockIdx.x];
  int i = blockIdx.x * 256 + t;
  if (i < N_NODES) {
    int r = partial[i] + add;
    rowptr[i] = r;
    cursor[i] = r;
  } else if (i == N_NODES) {
    rowptr[N_NODES] = N_EDGES;
  }
}

// ================================================================ prep + hist (one launch)
#define WP0 (128 * 96)
#define WP1 (128 * 256)
__global__ void prep_hist_kernel(const float* __restrict__ Wl0,
                                 const float* __restrict__ Wr0,
                                 const float* __restrict__ Wl,
                                 const float* __restrict__ Wr,
                                 const float* __restrict__ x,
                                 const int* __restrict__ dst,
                                 ushort_t* __restrict__ WT0,
                                 ushort_t* __restrict__ WT1,
                                 ushort_t* __restrict__ WT2,
                                 uint_t* __restrict__ xb,
                                 float* __restrict__ stats,
                                 int* __restrict__ degi, int prep_blocks) {
  if ((int)blockIdx.x >= prep_blocks) {
    const int nb = gridDim.x - prep_blocks;
    const int blk = blockIdx.x - prep_blocks;
    for (int e = blk * blockDim.x + threadIdx.x; e < N_EDGES;
         e += nb * blockDim.x)
      atomicAdd(&degi[dst[e]], 1);
    return;
  }
  int idx = blockIdx.x * blockDim.x + threadIdx.x;
  if (idx < 768) stats[idx] = 0.f;
  if (idx < WP0) {
    int c = idx / 96, k = idx - c * 96;
    float v = 0.f;
    if (k < 38) v = Wl0[k * 128 + c];
    else if (k < 76) v = Wr0[(k - 38) * 128 + c];
    WT0[(k >> 5) * 4096 + c * 32 + (k & 31)] = f2bf(v);
  } else if (idx < WP0 + 2 * WP1) {
    int i2 = idx - WP0;
    int layer = i2 / WP1;
    int j = i2 - layer * WP1;
    int c = j / 256, k = j - c * 256;
    const float* L = Wl + layer * 16384;
    const float* R = Wr + layer * 16384;
    float v = (k < 128) ? L[k * 128 + c] : R[(k - 128) * 128 + c];
    ushort_t* W = layer ? WT2 : WT1;
    W[(k >> 5) * 4096 + c * 32 + (k & 31)] = f2bf(v);
  } else if (idx < WP0 + 2 * WP1 + N_NODES * 20) {
    int j = idx - (WP0 + 2 * WP1);
    int row = j / 20, c2 = (j - row * 20) * 2;
    float v0 = (c2 < 38) ? x[row * 38 + c2] : 0.f;
    float v1 = (c2 + 1 < 38) ? x[row * 38 + c2 + 1] : 0.f;
    xb[j] = pack2(v0, v1);
  }
}

// ================================================================ layer-0 fused
// Gather (R12 form): 2 nodes/wave, lanes 0..18 own col-pairs, 4-deep unroll.
__global__ __launch_bounds__(256, 6) void gemm0_fused_kernel(
    const uint_t* __restrict__ xb, const int* __restrict__ rowptr,
    const ushort_t* __restrict__ col, const float* __restrict__ invdeg,
    const ushort_t* __restrict__ WT, ushort_t* __restrict__ P,
    float* __restrict__ stats) {
  __shared__ __align__(16) uint_t aggA[64 * 52];  // 64 rows x 96 bf16 + pad
  __shared__ __align__(16) ushort_t sB[128 * 40];
  const int tid = threadIdx.x;
  const int row0 = blockIdx.x * 64;
  const int w = tid >> 6;
  const int l = tid & 63;

  // ---- gather phase: 2 nodes per wave (32 lanes each), lanes 0..18 active
  {
    int half = l >> 5;
    int j = l & 31;
    for (int pass = 0; pass < 8; pass++) {
      int r = w * 16 + pass * 2 + half;
      int node = row0 + r;
      if (j < 19) {
        uint_t o = 0;
        if (node < N_NODES) {
          int beg = rowptr[node], end = rowptr[node + 1];
          float a0 = 0.f, a1 = 0.f;
          int e = beg;
          for (; e + 3 < end; e += 4) {
            uint_t u0 = xb[(size_t)col[e] * 20 + j];
            uint_t u1 = xb[(size_t)col[e + 1] * 20 + j];
            uint_t u2 = xb[(size_t)col[e + 2] * 20 + j];
            uint_t u3 = xb[(size_t)col[e + 3] * 20 + j];
            a0 += (bf_lo(u0) + bf_lo(u1)) + (bf_lo(u2) + bf_lo(u3));
            a1 += (bf_hi(u0) + bf_hi(u1)) + (bf_hi(u2) + bf_hi(u3));
          }
          for (; e < end; e++) {
            uint_t u = xb[(size_t)col[e] * 20 + j];
            a0 += bf_lo(u);
            a1 += bf_hi(u);
          }
          float inv = invdeg[node];
          o = pack2(a0 * inv, a1 * inv);
        }
        aggA[r * 52 + j] = o;
      }
    }
  }
  // ---- self + zero fill: uints 19..47 of each row
  for (int idx = tid; idx < 64 * 29; idx += 256) {
    int r = idx / 29;
    int j2 = idx - r * 29 + 19;
    int node = row0 + r;
    uint_t v = 0;
    if (node < N_NODES && j2 < 38) v = xb[(size_t)node * 20 + (j2 - 19)];
    aggA[r * 52 + j2] = v;
  }

  // ---- K loop (Kc = 96)
  const int m = l & 15;
  const int quad = l >> 4;
  f32x4 acc[8];
#pragma unroll
  for (int ct = 0; ct < 8; ct++) acc[ct] = (f32x4){0.f, 0.f, 0.f, 0.f};

  for (int kk = 0; kk < 96; kk += 32) {
    __syncthreads();
    {
      const uint4* wp = (const uint4*)(WT + (kk >> 5) * 4096);
      uint4 v0 = wp[tid];
      uint4 v1 = wp[tid + 256];
      *((uint4*)&sB[(tid >> 2) * 40 + (tid & 3) * 8]) = v0;
      int t2 = tid + 256;
      *((uint4*)&sB[(t2 >> 2) * 40 + (t2 & 3) * 8]) = v1;
    }
    __syncthreads();
    bf16x8 a = *(const bf16x8*)((const ushort_t*)aggA + (w * 16 + m) * 104 +
                                kk + quad * 8);
#pragma unroll
    for (int ct = 0; ct < 8; ct++) {
      bf16x8 b = *(const bf16x8*)&sB[(ct * 16 + m) * 40 + quad * 8];
      acc[ct] = __builtin_amdgcn_mfma_f32_16x16x32_bf16(a, b, acc[ct], 0, 0, 0);
    }
  }

#pragma unroll
  for (int ct = 0; ct < 8; ct++) {
#pragma unroll
    for (int v = 0; v < 4; v++) {
      int row = row0 + w * 16 + quad * 4 + v;
      if (row < N_NODES) P[(size_t)row * 128 + ct * 16 + m] = f2bf(acc[ct][v]);
    }
  }

  float* red = (float*)sB;
  __syncthreads();
#pragma unroll
  for (int ct = 0; ct < 8; ct++) {
    float s = 0.f, q = 0.f;
#pragma unroll
    for (int v = 0; v < 4; v++) {
      s += acc[ct][v];
      q += acc[ct][v] * acc[ct][v];
    }
    float t;
    t = __shfl_xor(s, 16); s += t;
    t = __shfl_xor(s, 32); s += t;
    t = __shfl_xor(q, 16); q += t;
    t = __shfl_xor(q, 32); q += t;
    if (l < 16) {
      red[w * 256 + ct * 16 + l] = s;
      red[w * 256 + 128 + ct * 16 + l] = q;
    }
  }
  __syncthreads();
  if (tid < 128) {
    float s = 0.f, q = 0.f;
#pragma unroll
    for (int wv = 0; wv < 4; wv++) {
      s += red[wv * 256 + tid];
      q += red[wv * 256 + 128 + tid];
    }
    atomicAdd(&stats[tid], s);
    atomicAdd(&stats[128 + tid], q);
  }
}

// ================================================================ fused layer kernel
// gather with 8-deep unroll (8 independent uint4 loads in flight per lane);
// self rows (k>=128) loaded before gather to overlap latency.
__global__ __launch_bounds__(256, 5) void gemm_fused_kernel(
    const ushort_t* __restrict__ Pin, const float* __restrict__ stats_prev,
    const float* __restrict__ gamma, const float* __restrict__ beta,
    const int* __restrict__ rowptr, const ushort_t* __restrict__ col,
    const float* __restrict__ invdeg, const ushort_t* __restrict__ WT,
    ushort_t* __restrict__ Pout, float* __restrict__ stats_out) {
  __shared__ __align__(16) uint_t aggu[64 * 68];
  __shared__ __align__(16) ushort_t sB[128 * 40];
  __shared__ float ssc[256];
  const int tid = threadIdx.x;
  const int row0 = blockIdx.x * 64;

  if (tid < 128) {
    const float invN = 1.0f / (float)N_NODES;
    float mean = stats_prev[tid] * invN;
    float var = stats_prev[128 + tid] * invN - mean * mean;
    float scale = gamma[tid] * rsqrtf(var + BN_EPS);
    ssc[tid] = scale;
    ssc[128 + tid] = beta[tid] - mean * scale;
  }
  __syncthreads();

  const int w = tid >> 6;
  const int l = tid & 63;
  const int m = l & 15;
  const int quad = l >> 4;

  // ---- self rows raw load first (latency overlaps gather below)
  const int srow = row0 + w * 16 + m;
  uint4 selfraw[4];
#pragma unroll
  for (int i = 0; i < 4; i++) {
    selfraw[i] = make_uint4(0, 0, 0, 0);
    if (srow < N_NODES)
      selfraw[i] = *(const uint4*)(Pin + (size_t)srow * 128 + i * 32 + quad * 8);
  }

  // ---- gather phase: 16 groups of 16 lanes, 4 nodes each, 8-deep unroll
  const int g2 = (tid >> 4) & 3;
  const int h = tid & 15;
  const uint4* Pu = (const uint4*)Pin;  // row stride 16 uint4
  {
    int c0 = h * 8;
    float s[8], b[8];
#pragma unroll
    for (int j = 0; j < 8; j++) {
      s[j] = ssc[c0 + j];
      b[j] = ssc[128 + c0 + j];
    }
    for (int pass = 0; pass < 4; pass++) {
      int r = w * 16 + pass * 4 + g2;
      int node = row0 + r;
      uint4 o = make_uint4(0, 0, 0, 0);
      if (node < N_NODES) {
        int beg = rowptr[node], end = rowptr[node + 1];
        float a[8];
#pragma unroll
        for (int j = 0; j < 8; j++) a[j] = 0.f;
        int e = beg;
        for (; e + 7 < end; e += 8) {
          uint4 u[8];
#pragma unroll
          for (int q8 = 0; q8 < 8; q8++)
            u[q8] = Pu[(size_t)col[e + q8] * 16 + h];
#pragma unroll
          for (int q8 = 0; q8 < 8; q8++) {
            uint_t ww[4] = {u[q8].x, u[q8].y, u[q8].z, u[q8].w};
#pragma unroll
            for (int p = 0; p < 4; p++) {
              a[2 * p]     += fmaxf(bf_lo(ww[p]) * s[2 * p] + b[2 * p], 0.f);
              a[2 * p + 1] += fmaxf(bf_hi(ww[p]) * s[2 * p + 1] + b[2 * p + 1], 0.f);
            }
          }
        }
        for (; e + 3 < end; e += 4) {
          uint4 u[4];
#pragma unroll
          for (int q4 = 0; q4 < 4; q4++)
            u[q4] = Pu[(size_t)col[e + q4] * 16 + h];
#pragma unroll
          for (int q4 = 0; q4 < 4; q4++) {
            uint_t ww[4] = {u[q4].x, u[q4].y, u[q4].z, u[q4].w};
#pragma unroll
            for (int p = 0; p < 4; p++) {
              a[2 * p]     += fmaxf(bf_lo(ww[p]) * s[2 * p] + b[2 * p], 0.f);
              a[2 * p + 1] += fmaxf(bf_hi(ww[p]) * s[2 * p + 1] + b[2 * p + 1], 0.f);
            }
          }
        }
        for (; e < end; e++) {
          uint4 u = Pu[(size_t)col[e] * 16 + h];
          uint_t ww[4] = {u.x, u.y, u.z, u.w};
#pragma unroll
          for (int p = 0; p < 4; p++) {
            a[2 * p]     += fmaxf(bf_lo(ww[p]) * s[2 * p] + b[2 * p], 0.f);
            a[2 * p + 1] += fmaxf(bf_hi(ww[p]) * s[2 * p + 1] + b[2 * p + 1], 0.f);
          }
        }
        float inv = invdeg[node];
        o.x = pack2(a[0] * inv, a[1] * inv);
        o.y = pack2(a[2] * inv, a[3] * inv);
        o.z = pack2(a[4] * inv, a[5] * inv);
        o.w = pack2(a[6] * inv, a[7] * inv);
      }
      *((uint4*)&aggu[r * 68 + h * 4]) = o;
    }
  }

  // ---- BN-transform self rows in registers
  uint4 selfbn[4];
#pragma unroll
  for (int i = 0; i < 4; i++) {
    int cc = i * 32 + quad * 8;
    uint_t in[4] = {selfraw[i].x, selfraw[i].y, selfraw[i].z, selfraw[i].w};
    uint_t ov[4];
#pragma unroll
    for (int p = 0; p < 4; p++) {
      float f0 = fmaxf(bf_lo(in[p]) * ssc[cc + 2 * p] + ssc[128 + cc + 2 * p], 0.f);
      float f1 = fmaxf(bf_hi(in[p]) * ssc[cc + 2 * p + 1] + ssc[128 + cc + 2 * p + 1], 0.f);
      ov[p] = pack2(f0, f1);
    }
    selfbn[i] = make_uint4(ov[0], ov[1], ov[2], ov[3]);
  }

  // ---- K loop
  f32x4 acc[8];
#pragma unroll
  for (int ct = 0; ct < 8; ct++) acc[ct] = (f32x4){0.f, 0.f, 0.f, 0.f};

  for (int kk = 0; kk < 256; kk += 32) {
    __syncthreads();
    {
      const uint4* wp = (const uint4*)(WT + (kk >> 5) * 4096);
      uint4 v0 = wp[tid];
      uint4 v1 = wp[tid + 256];
      *((uint4*)&sB[(tid >> 2) * 40 + (tid & 3) * 8]) = v0;
      int t2 = tid + 256;
      *((uint4*)&sB[(t2 >> 2) * 40 + (t2 & 3) * 8]) = v1;
    }
    __syncthreads();
    bf16x8 a;
    if (kk < 128) {
      a = *(const bf16x8*)((const ushort_t*)aggu + (w * 16 + m) * 136 + kk + quad * 8);
    } else {
      uint4 vv = selfbn[(kk - 128) >> 5];
      a = *(bf16x8*)&vv;
    }
#pragma unroll
    for (int ct = 0; ct < 8; ct++) {
      bf16x8 bb = *(const bf16x8*)&sB[(ct * 16 + m) * 40 + quad * 8];
      acc[ct] = __builtin_amdgcn_mfma_f32_16x16x32_bf16(a, bb, acc[ct], 0, 0, 0);
    }
  }

#pragma unroll
  for (int ct = 0; ct < 8; ct++) {
#pragma unroll
    for (int v = 0; v < 4; v++) {
      int row = row0 + w * 16 + quad * 4 + v;
      if (row < N_NODES) Pout[(size_t)row * 128 + ct * 16 + m] = f2bf(acc[ct][v]);
    }
  }

  float* red = (float*)sB;
  __syncthreads();
#pragma unroll
  for (int ct = 0; ct < 8; ct++) {
    float ss = 0.f, q = 0.f;
#pragma unroll
    for (int v = 0; v < 4; v++) {
      ss += acc[ct][v];
      q += acc[ct][v] * acc[ct][v];
    }
    float t;
    t = __shfl_xor(ss, 16); ss += t;
    t = __shfl_xor(ss, 32); ss += t;
    t = __shfl_xor(q, 16); q += t;
    t = __shfl_xor(q, 32); q += t;
    if (l < 16) {
      red[w * 256 + ct * 16 + l] = ss;
      red[w * 256 + 128 + ct * 16 + l] = q;
    }
  }
  __syncthreads();
  if (tid < 128) {
    float ss = 0.f, q = 0.f;
#pragma unroll
    for (int wv = 0; wv < 4; wv++) {
      ss += red[wv * 256 + tid];
      q += red[wv * 256 + 128 + tid];
    }
    atomicAdd(&stats_out[tid], ss);
    atomicAdd(&stats_out[128 + tid], q);
  }
}

// ================================================================ pool + readout
__global__ __launch_bounds__(128) void pool_readout_kernel(
    const ushort_t* __restrict__ P, const float* __restrict__ stats,
    const float* __restrict__ gamma, const float* __restrict__ beta,
    const int* __restrict__ batch, const float* __restrict__ rW1,
    const float* __restrict__ rb1, const float* __restrict__ rW2,
    const float* __restrict__ rb2, float* __restrict__ out) {
  int g = blockIdx.x;
  int t = threadIdx.x;
  int lo = 0, hi = N_NODES;
  while (lo < hi) { int mid = (lo + hi) >> 1; if (batch[mid] < g) lo = mid + 1; else hi = mid; }
  int gs = lo;
  hi = N_NODES;
  while (lo < hi) { int mid = (lo + hi) >> 1; if (batch[mid] < g + 1) lo = mid + 1; else hi = mid; }
  int ge = lo;
  const float invN = 1.0f / (float)N_NODES;
  float mean = stats[t] * invN;
  float var = stats[128 + t] * invN - mean * mean;
  float s = gamma[t] * rsqrtf(var + BN_EPS);
  float b = beta[t] - mean * s;
  float acc = 0.f;
  const ushort_t* pr = P + (size_t)gs * 128 + t;
  for (int r = gs; r < ge; r++, pr += 128)
    acc += fmaxf(__uint_as_float(((uint_t)*pr) << 16) * s + b, 0.f);
  __shared__ float pl[128];
  pl[t] = acc / fmaxf((float)(ge - gs), 1.f);
  __syncthreads();
  if (t < 64) {
    float h1 = rb1[t];
    for (int k = 0; k < 128; k++) h1 += pl[k] * rW1[k * 64 + t];
    h1 = fmaxf(h1, 0.f) * rW2[t];
#pragma unroll
    for (int off = 32; off > 0; off >>= 1) h1 += __shfl_down(h1, off);
    if (t == 0) out[g] = h1 + rb2[0];
  }
}

// ================================================================ launch
extern "C" void kernel_launch(void* const* d_in, const int* in_sizes, int n_in,
                              void* d_out, int out_size, void* d_ws, size_t ws_size,
                              hipStream_t stream) {
  const float* x     = (const float*)d_in[0];
  const int*   ei    = (const int*)d_in[1];
  const int*   src   = ei;
  const int*   dst   = ei + N_EDGES;
  const int*   batch = (const int*)d_in[2];
  const float* Wl0   = (const float*)d_in[3];
  const float* Wr0   = (const float*)d_in[4];
  const float* Wl    = (const float*)d_in[6];
  const float* Wr    = (const float*)d_in[7];
  const float* gamma = (const float*)d_in[9];
  const float* beta  = (const float*)d_in[10];
  const float* rW1   = (const float*)d_in[11];
  const float* rb1   = (const float*)d_in[12];
  const float* rW2   = (const float*)d_in[13];
  const float* rb2   = (const float*)d_in[14];
  float* out = (float*)d_out;

  char* ws = (char*)d_ws;
  size_t off = 0;
  auto alloc = [&](size_t bytes) -> void* {
    void* p = ws + off;
    off = (off + bytes + 255) & ~(size_t)255;
    return p;
  };
  uint_t*   xb    = (uint_t*)alloc((size_t)N_NODES * 20 * 4);
  ushort_t* Pa    = (ushort_t*)alloc((size_t)N_NODES * 128 * 2);
  ushort_t* Pb    = (ushort_t*)alloc((size_t)N_NODES * 128 * 2);
  ushort_t* WT0   = (ushort_t*)alloc((size_t)128 * 96 * 2);
  ushort_t* WT1   = (ushort_t*)alloc((size_t)128 * 256 * 2);
  ushort_t* WT2   = (ushort_t*)alloc((size_t)128 * 256 * 2);
  float* invdeg = (float*)alloc((size_t)N_NODES * 4);
  int*   degi   = (int*)alloc((size_t)N_NODES * 4);
  int*   rowptr = (int*)alloc((size_t)(N_NODES + 1) * 4);
  int*   cursor = (int*)alloc((size_t)N_NODES * 4);
  ushort_t* colidx = (ushort_t*)alloc((size_t)N_EDGES * 2);
  int*   partial= (int*)alloc((size_t)N_NODES * 4);
  int*   bsum   = (int*)alloc(256 * 4);
  float* stats  = (float*)alloc(768 * 4);  // 3 layers x {sum[128],sumsq[128]}

  const int NB_SCAN = (N_NODES + 255) / 256;  // 196
  const int gemm_blocks = (N_NODES + 63) / 64;
  const int PREP_TOTAL = WP0 + 2 * WP1 + N_NODES * 20;
  const int PREP_BLOCKS = (PREP_TOTAL + 255) / 256;
  const int HIST_BLOCKS = 512;

  // ---- prep (weights/xb/stats) + histogram in one launch
  hipMemsetAsync(degi, 0, (size_t)N_NODES * 4, stream);
  prep_hist_kernel<<<PREP_BLOCKS + HIST_BLOCKS, 256, 0, stream>>>(
      Wl0, Wr0, Wl, Wr, x, dst, WT0, WT1, WT2, xb, stats, degi, PREP_BLOCKS);

  // ---- CSR build
  scan_block_kernel<<<NB_SCAN, 256, 0, stream>>>(degi, partial, bsum, invdeg);
  scan_add_fused_kernel<<<NB_SCAN + 1, 256, 0, stream>>>(partial, bsum, rowptr,
                                                         cursor, NB_SCAN);
  fill_sharded_kernel<<<2048, 256, 0, stream>>>(src, dst, cursor, colidx);

  // ---- layer 0 (fused gather + GEMM)
  gemm0_fused_kernel<<<gemm_blocks, 256, 0, stream>>>(xb, rowptr, colidx, invdeg,
                                                      WT0, Pa, stats);

  // ---- layer 1: Pa -> Pb
  gemm_fused_kernel<<<gemm_blocks, 256, 0, stream>>>(
      Pa, stats, gamma, beta, rowptr, colidx, invdeg, WT1, Pb, stats + 256);

  // ---- layer 2: Pb -> Pa
  gemm_fused_kernel<<<gemm_blocks, 256, 0, stream>>>(
      Pb, stats + 256, gamma + 128, beta + 128, rowptr, colidx, invdeg, WT2,
      Pa, stats + 512);

  // ---- fused global mean pool (final BN inline) + readout
  pool_readout_kernel<<<N_GRAPHS, 128, 0, stream>>>(
      Pa, stats + 512, gamma + 256, beta + 256, batch, rW1, rb1, rW2, rb2, out);
}

// Round 15
// 366.019 us; speedup vs baseline: 1.0553x; 1.0553x over previous
//
#include <hip/hip_runtime.h>

#define N_NODES 50000
#define N_EDGES 800000
#define N_GRAPHS 2000
#define BN_EPS 1e-5f
#define FSHARD 12500  // fill: N_NODES / 4

typedef unsigned short ushort_t;
typedef unsigned int uint_t;
using bf16x8 = __attribute__((ext_vector_type(8))) short;
using f32x4  = __attribute__((ext_vector_type(4))) float;

__device__ inline float bf_lo(uint_t u) { return __uint_as_float(u << 16); }
__device__ inline float bf_hi(uint_t u) { return __uint_as_float(u & 0xffff0000u); }
__device__ inline ushort_t f2bf(float f) {  // round-to-nearest-even
  uint_t u = __float_as_uint(f);
  return (ushort_t)((u + 0x7fffu + ((u >> 16) & 1u)) >> 16);
}
__device__ inline uint_t pack2(float a, float b) {
  return (uint_t)f2bf(a) | ((uint_t)f2bf(b) << 16);
}

// ================================================================ CSR build
__global__ void fill_sharded_kernel(const int* __restrict__ src,
                                    const int* __restrict__ dst,
                                    int* __restrict__ cursor,
                                    ushort_t* __restrict__ col) {
  const int shard = blockIdx.x & 3;
  const int lo = shard * FSHARD, hi = lo + FSHARD;
  const int nb = gridDim.x >> 2, blk = blockIdx.x >> 2;
  for (int e = blk * blockDim.x + threadIdx.x; e < N_EDGES;
       e += nb * blockDim.x) {
    int d = dst[e];
    if (d >= lo && d < hi) {
      int p = atomicAdd(&cursor[d], 1);
      col[p] = (ushort_t)src[e];
    }
  }
}

__global__ void scan_block_kernel(const int* __restrict__ degi,
                                  int* __restrict__ partial,
                                  int* __restrict__ bsum,
                                  float* __restrict__ invdeg) {
  __shared__ int buf[2][256];
  int i = blockIdx.x * 256 + threadIdx.x;
  int v = (i < N_NODES) ? degi[i] : 0;
  buf[0][threadIdx.x] = v;
  __syncthreads();
  int pi = 0;
  for (int off = 1; off < 256; off <<= 1) {
    int nv = buf[pi][threadIdx.x];
    if (threadIdx.x >= off) nv += buf[pi][threadIdx.x - off];
    buf[pi ^ 1][threadIdx.x] = nv;
    pi ^= 1;
    __syncthreads();
  }
  int incl = buf[pi][threadIdx.x];
  if (i < N_NODES) {
    partial[i] = incl - v;
    invdeg[i] = 1.0f / fmaxf((float)v, 1.0f);
  }
  if (threadIdx.x == 255) bsum[blockIdx.x] = incl;
}

__global__ void scan_add_fused_kernel(const int* __restrict__ partial,
                                      const int* __restrict__ bsum,
                                      int* __restrict__ rowptr,
                                      int* __restrict__ cursor, int nb) {
  __shared__ int buf[2][256];
  __shared__ int sx[256];
  int t = threadIdx.x;
  int v = (t < nb) ? bsum[t] : 0;
  buf[0][t] = v;
  __syncthreads();
  int pi = 0;
  for (int off = 1; off < 256; off <<= 1) {
    int nv = buf[pi][t];
    if (t >= off) nv += buf[pi][t - off];
    buf[pi ^ 1][t] = nv;
    pi ^= 1;
    __syncthreads();
  }
  sx[t] = buf[pi][t] - v;
  __syncthreads();
  int add = sx[blockIdx.x];
  int i = blockIdx.x * 256 + t;
  if (i < N_NODES) {
    int r = partial[i] + add;
    rowptr[i] = r;
    cursor[i] = r;
  } else if (i == N_NODES) {
    rowptr[N_NODES] = N_EDGES;
  }
}

// ================================================================ prep + hist (one launch)
#define WP0 (128 * 96)
#define WP1 (128 * 256)
__global__ void prep_hist_kernel(const float* __restrict__ Wl0,
                                 const float* __restrict__ Wr0,
                                 const float* __restrict__ Wl,
                                 const float* __restrict__ Wr,
                                 const float* __restrict__ x,
                                 const int* __restrict__ dst,
                                 ushort_t* __restrict__ WT0,
                                 ushort_t* __restrict__ WT1,
                                 ushort_t* __restrict__ WT2,
                                 uint_t* __restrict__ xb,
                                 float* __restrict__ stats,
                                 int* __restrict__ degi, int prep_blocks) {
  if ((int)blockIdx.x >= prep_blocks) {
    const int nb = gridDim.x - prep_blocks;
    const int blk = blockIdx.x - prep_blocks;
    for (int e = blk * blockDim.x + threadIdx.x; e < N_EDGES;
         e += nb * blockDim.x)
      atomicAdd(&degi[dst[e]], 1);
    return;
  }
  int idx = blockIdx.x * blockDim.x + threadIdx.x;
  if (idx < 768) stats[idx] = 0.f;
  if (idx < WP0) {
    int c = idx / 96, k = idx - c * 96;
    float v = 0.f;
    if (k < 38) v = Wl0[k * 128 + c];
    else if (k < 76) v = Wr0[(k - 38) * 128 + c];
    WT0[(k >> 5) * 4096 + c * 32 + (k & 31)] = f2bf(v);
  } else if (idx < WP0 + 2 * WP1) {
    int i2 = idx - WP0;
    int layer = i2 / WP1;
    int j = i2 - layer * WP1;
    int c = j / 256, k = j - c * 256;
    const float* L = Wl + layer * 16384;
    const float* R = Wr + layer * 16384;
    float v = (k < 128) ? L[k * 128 + c] : R[(k - 128) * 128 + c];
    ushort_t* W = layer ? WT2 : WT1;
    W[(k >> 5) * 4096 + c * 32 + (k & 31)] = f2bf(v);
  } else if (idx < WP0 + 2 * WP1 + N_NODES * 20) {
    int j = idx - (WP0 + 2 * WP1);
    int row = j / 20, c2 = (j - row * 20) * 2;
    float v0 = (c2 < 38) ? x[row * 38 + c2] : 0.f;
    float v1 = (c2 + 1 < 38) ? x[row * 38 + c2 + 1] : 0.f;
    xb[j] = pack2(v0, v1);
  }
}

// ================================================================ layer-0 fused
// Gather (R12 form): 2 nodes/wave, lanes 0..18 own col-pairs, 4-deep unroll.
__global__ __launch_bounds__(256, 6) void gemm0_fused_kernel(
    const uint_t* __restrict__ xb, const int* __restrict__ rowptr,
    const ushort_t* __restrict__ col, const float* __restrict__ invdeg,
    const ushort_t* __restrict__ WT, ushort_t* __restrict__ P,
    float* __restrict__ stats) {
  __shared__ __align__(16) uint_t aggA[64 * 52];  // 64 rows x 96 bf16 + pad
  __shared__ __align__(16) ushort_t sB[128 * 40];
  const int tid = threadIdx.x;
  const int row0 = blockIdx.x * 64;
  const int w = tid >> 6;
  const int l = tid & 63;

  // ---- gather phase: 2 nodes per wave (32 lanes each), lanes 0..18 active
  {
    int half = l >> 5;
    int j = l & 31;
    for (int pass = 0; pass < 8; pass++) {
      int r = w * 16 + pass * 2 + half;
      int node = row0 + r;
      if (j < 19) {
        uint_t o = 0;
        if (node < N_NODES) {
          int beg = rowptr[node], end = rowptr[node + 1];
          float a0 = 0.f, a1 = 0.f;
          int e = beg;
          for (; e + 3 < end; e += 4) {
            uint_t u0 = xb[(size_t)col[e] * 20 + j];
            uint_t u1 = xb[(size_t)col[e + 1] * 20 + j];
            uint_t u2 = xb[(size_t)col[e + 2] * 20 + j];
            uint_t u3 = xb[(size_t)col[e + 3] * 20 + j];
            a0 += (bf_lo(u0) + bf_lo(u1)) + (bf_lo(u2) + bf_lo(u3));
            a1 += (bf_hi(u0) + bf_hi(u1)) + (bf_hi(u2) + bf_hi(u3));
          }
          for (; e < end; e++) {
            uint_t u = xb[(size_t)col[e] * 20 + j];
            a0 += bf_lo(u);
            a1 += bf_hi(u);
          }
          float inv = invdeg[node];
          o = pack2(a0 * inv, a1 * inv);
        }
        aggA[r * 52 + j] = o;
      }
    }
  }
  // ---- self + zero fill: uints 19..47 of each row
  for (int idx = tid; idx < 64 * 29; idx += 256) {
    int r = idx / 29;
    int j2 = idx - r * 29 + 19;
    int node = row0 + r;
    uint_t v = 0;
    if (node < N_NODES && j2 < 38) v = xb[(size_t)node * 20 + (j2 - 19)];
    aggA[r * 52 + j2] = v;
  }

  // ---- K loop (Kc = 96)
  const int m = l & 15;
  const int quad = l >> 4;
  f32x4 acc[8];
#pragma unroll
  for (int ct = 0; ct < 8; ct++) acc[ct] = (f32x4){0.f, 0.f, 0.f, 0.f};

  for (int kk = 0; kk < 96; kk += 32) {
    __syncthreads();
    {
      const uint4* wp = (const uint4*)(WT + (kk >> 5) * 4096);
      uint4 v0 = wp[tid];
      uint4 v1 = wp[tid + 256];
      *((uint4*)&sB[(tid >> 2) * 40 + (tid & 3) * 8]) = v0;
      int t2 = tid + 256;
      *((uint4*)&sB[(t2 >> 2) * 40 + (t2 & 3) * 8]) = v1;
    }
    __syncthreads();
    bf16x8 a = *(const bf16x8*)((const ushort_t*)aggA + (w * 16 + m) * 104 +
                                kk + quad * 8);
#pragma unroll
    for (int ct = 0; ct < 8; ct++) {
      bf16x8 b = *(const bf16x8*)&sB[(ct * 16 + m) * 40 + quad * 8];
      acc[ct] = __builtin_amdgcn_mfma_f32_16x16x32_bf16(a, b, acc[ct], 0, 0, 0);
    }
  }

#pragma unroll
  for (int ct = 0; ct < 8; ct++) {
#pragma unroll
    for (int v = 0; v < 4; v++) {
      int row = row0 + w * 16 + quad * 4 + v;
      if (row < N_NODES) P[(size_t)row * 128 + ct * 16 + m] = f2bf(acc[ct][v]);
    }
  }

  float* red = (float*)sB;
  __syncthreads();
#pragma unroll
  for (int ct = 0; ct < 8; ct++) {
    float s = 0.f, q = 0.f;
#pragma unroll
    for (int v = 0; v < 4; v++) {
      s += acc[ct][v];
      q += acc[ct][v] * acc[ct][v];
    }
    float t;
    t = __shfl_xor(s, 16); s += t;
    t = __shfl_xor(s, 32); s += t;
    t = __shfl_xor(q, 16); q += t;
    t = __shfl_xor(q, 32); q += t;
    if (l < 16) {
      red[w * 256 + ct * 16 + l] = s;
      red[w * 256 + 128 + ct * 16 + l] = q;
    }
  }
  __syncthreads();
  if (tid < 128) {
    float s = 0.f, q = 0.f;
#pragma unroll
    for (int wv = 0; wv < 4; wv++) {
      s += red[wv * 256 + tid];
      q += red[wv * 256 + 128 + tid];
    }
    atomicAdd(&stats[tid], s);
    atomicAdd(&stats[128 + tid], q);
  }
}

// ================================================================ fused layer kernel
// R12 form: gather-aggregate relu(Pin*s+b) into LDS aggu (4-deep unroll),
// K-loop with sA staging for k>=128 (BN on the fly), stats epilogue.
__global__ __launch_bounds__(256, 4) void gemm_fused_kernel(
    const ushort_t* __restrict__ Pin, const float* __restrict__ stats_prev,
    const float* __restrict__ gamma, const float* __restrict__ beta,
    const int* __restrict__ rowptr, const ushort_t* __restrict__ col,
    const float* __restrict__ invdeg, const ushort_t* __restrict__ WT,
    ushort_t* __restrict__ Pout, float* __restrict__ stats_out) {
  __shared__ __align__(16) uint_t aggu[64 * 68];
  __shared__ __align__(16) ushort_t sA[64 * 40];
  __shared__ __align__(16) ushort_t sB[128 * 40];
  __shared__ float ssc[256];
  const int tid = threadIdx.x;
  const int row0 = blockIdx.x * 64;

  if (tid < 128) {
    const float invN = 1.0f / (float)N_NODES;
    float mean = stats_prev[tid] * invN;
    float var = stats_prev[128 + tid] * invN - mean * mean;
    float scale = gamma[tid] * rsqrtf(var + BN_EPS);
    ssc[tid] = scale;
    ssc[128 + tid] = beta[tid] - mean * scale;
  }
  __syncthreads();

  const int w = tid >> 6;
  const int g2 = (tid >> 4) & 3;
  const int h = tid & 15;
  const uint4* Pu = (const uint4*)Pin;  // row stride 16 uint4
  {
    int c0 = h * 8;
    float s[8], b[8];
#pragma unroll
    for (int j = 0; j < 8; j++) {
      s[j] = ssc[c0 + j];
      b[j] = ssc[128 + c0 + j];
    }
    for (int pass = 0; pass < 4; pass++) {
      int r = w * 16 + pass * 4 + g2;
      int node = row0 + r;
      uint4 o = make_uint4(0, 0, 0, 0);
      if (node < N_NODES) {
        int beg = rowptr[node], end = rowptr[node + 1];
        float a[8];
#pragma unroll
        for (int j = 0; j < 8; j++) a[j] = 0.f;
        int e = beg;
        for (; e + 3 < end; e += 4) {
          uint4 u0 = Pu[(size_t)col[e] * 16 + h];
          uint4 u1 = Pu[(size_t)col[e + 1] * 16 + h];
          uint4 u2 = Pu[(size_t)col[e + 2] * 16 + h];
          uint4 u3 = Pu[(size_t)col[e + 3] * 16 + h];
          uint_t w0[4] = {u0.x, u0.y, u0.z, u0.w};
          uint_t w1[4] = {u1.x, u1.y, u1.z, u1.w};
          uint_t w2[4] = {u2.x, u2.y, u2.z, u2.w};
          uint_t w3[4] = {u3.x, u3.y, u3.z, u3.w};
#pragma unroll
          for (int p = 0; p < 4; p++) {
            a[2 * p]     += (fmaxf(bf_lo(w0[p]) * s[2 * p] + b[2 * p], 0.f) +
                             fmaxf(bf_lo(w1[p]) * s[2 * p] + b[2 * p], 0.f)) +
                            (fmaxf(bf_lo(w2[p]) * s[2 * p] + b[2 * p], 0.f) +
                             fmaxf(bf_lo(w3[p]) * s[2 * p] + b[2 * p], 0.f));
            a[2 * p + 1] += (fmaxf(bf_hi(w0[p]) * s[2 * p + 1] + b[2 * p + 1], 0.f) +
                             fmaxf(bf_hi(w1[p]) * s[2 * p + 1] + b[2 * p + 1], 0.f)) +
                            (fmaxf(bf_hi(w2[p]) * s[2 * p + 1] + b[2 * p + 1], 0.f) +
                             fmaxf(bf_hi(w3[p]) * s[2 * p + 1] + b[2 * p + 1], 0.f));
          }
        }
        for (; e < end; e++) {
          uint4 u = Pu[(size_t)col[e] * 16 + h];
          uint_t ww[4] = {u.x, u.y, u.z, u.w};
#pragma unroll
          for (int p = 0; p < 4; p++) {
            a[2 * p]     += fmaxf(bf_lo(ww[p]) * s[2 * p] + b[2 * p], 0.f);
            a[2 * p + 1] += fmaxf(bf_hi(ww[p]) * s[2 * p + 1] + b[2 * p + 1], 0.f);
          }
        }
        float inv = invdeg[node];
        o.x = pack2(a[0] * inv, a[1] * inv);
        o.y = pack2(a[2] * inv, a[3] * inv);
        o.z = pack2(a[4] * inv, a[5] * inv);
        o.w = pack2(a[6] * inv, a[7] * inv);
      }
      *((uint4*)&aggu[r * 68 + h * 4]) = o;
    }
  }
  __syncthreads();

  const int l = tid & 63;
  const int m = l & 15;
  const int quad = l >> 4;
  f32x4 acc[8];
#pragma unroll
  for (int ct = 0; ct < 8; ct++) acc[ct] = (f32x4){0.f, 0.f, 0.f, 0.f};

  for (int kk = 0; kk < 256; kk += 32) {
    __syncthreads();
    {
      const uint4* wp = (const uint4*)(WT + (kk >> 5) * 4096);
      uint4 v0 = wp[tid];
      uint4 v1 = wp[tid + 256];
      *((uint4*)&sB[(tid >> 2) * 40 + (tid & 3) * 8]) = v0;
      int t2 = tid + 256;
      *((uint4*)&sB[(t2 >> 2) * 40 + (t2 & 3) * 8]) = v1;
    }
    if (kk >= 128) {
      int r = tid >> 2, c = tid & 3;
      int row = row0 + r;
      uint4 v = make_uint4(0, 0, 0, 0);
      if (row < N_NODES) {
        int pcol = kk - 128 + c * 8;
        uint4 u = *(const uint4*)(Pin + (size_t)row * 128 + pcol);
        uint_t in[4] = {u.x, u.y, u.z, u.w};
        uint_t ov[4];
#pragma unroll
        for (int p = 0; p < 4; p++) {
          int cc = pcol + 2 * p;
          float f0 = fmaxf(bf_lo(in[p]) * ssc[cc] + ssc[128 + cc], 0.f);
          float f1 = fmaxf(bf_hi(in[p]) * ssc[cc + 1] + ssc[128 + cc + 1], 0.f);
          ov[p] = pack2(f0, f1);
        }
        v = make_uint4(ov[0], ov[1], ov[2], ov[3]);
      }
      *((uint4*)&sA[r * 40 + c * 8]) = v;
    }
    __syncthreads();
    bf16x8 a;
    if (kk < 128)
      a = *(const bf16x8*)((const ushort_t*)aggu + (w * 16 + m) * 136 + kk + quad * 8);
    else
      a = *(const bf16x8*)&sA[(w * 16 + m) * 40 + quad * 8];
#pragma unroll
    for (int ct = 0; ct < 8; ct++) {
      bf16x8 bb = *(const bf16x8*)&sB[(ct * 16 + m) * 40 + quad * 8];
      acc[ct] = __builtin_amdgcn_mfma_f32_16x16x32_bf16(a, bb, acc[ct], 0, 0, 0);
    }
  }

#pragma unroll
  for (int ct = 0; ct < 8; ct++) {
#pragma unroll
    for (int v = 0; v < 4; v++) {
      int row = row0 + w * 16 + quad * 4 + v;
      if (row < N_NODES) Pout[(size_t)row * 128 + ct * 16 + m] = f2bf(acc[ct][v]);
    }
  }

  float* red = (float*)sA;
  __syncthreads();
#pragma unroll
  for (int ct = 0; ct < 8; ct++) {
    float ss = 0.f, q = 0.f;
#pragma unroll
    for (int v = 0; v < 4; v++) {
      ss += acc[ct][v];
      q += acc[ct][v] * acc[ct][v];
    }
    float t;
    t = __shfl_xor(ss, 16); ss += t;
    t = __shfl_xor(ss, 32); ss += t;
    t = __shfl_xor(q, 16); q += t;
    t = __shfl_xor(q, 32); q += t;
    if (l < 16) {
      red[w * 256 + ct * 16 + l] = ss;
      red[w * 256 + 128 + ct * 16 + l] = q;
    }
  }
  __syncthreads();
  if (tid < 128) {
    float ss = 0.f, q = 0.f;
#pragma unroll
    for (int wv = 0; wv < 4; wv++) {
      ss += red[wv * 256 + tid];
      q += red[wv * 256 + 128 + tid];
    }
    atomicAdd(&stats_out[tid], ss);
    atomicAdd(&stats_out[128 + tid], q);
  }
}

// ================================================================ pool + readout
__global__ __launch_bounds__(128) void pool_readout_kernel(
    const ushort_t* __restrict__ P, const float* __restrict__ stats,
    const float* __restrict__ gamma, const float* __restrict__ beta,
    const int* __restrict__ batch, const float* __restrict__ rW1,
    const float* __restrict__ rb1, const float* __restrict__ rW2,
    const float* __restrict__ rb2, float* __restrict__ out) {
  int g = blockIdx.x;
  int t = threadIdx.x;
  int lo = 0, hi = N_NODES;
  while (lo < hi) { int mid = (lo + hi) >> 1; if (batch[mid] < g) lo = mid + 1; else hi = mid; }
  int gs = lo;
  hi = N_NODES;
  while (lo < hi) { int mid = (lo + hi) >> 1; if (batch[mid] < g + 1) lo = mid + 1; else hi = mid; }
  int ge = lo;
  const float invN = 1.0f / (float)N_NODES;
  float mean = stats[t] * invN;
  float var = stats[128 + t] * invN - mean * mean;
  float s = gamma[t] * rsqrtf(var + BN_EPS);
  float b = beta[t] - mean * s;
  float acc = 0.f;
  const ushort_t* pr = P + (size_t)gs * 128 + t;
  for (int r = gs; r < ge; r++, pr += 128)
    acc += fmaxf(__uint_as_float(((uint_t)*pr) << 16) * s + b, 0.f);
  __shared__ float pl[128];
  pl[t] = acc / fmaxf((float)(ge - gs), 1.f);
  __syncthreads();
  if (t < 64) {
    float h1 = rb1[t];
    for (int k = 0; k < 128; k++) h1 += pl[k] * rW1[k * 64 + t];
    h1 = fmaxf(h1, 0.f) * rW2[t];
#pragma unroll
    for (int off = 32; off > 0; off >>= 1) h1 += __shfl_down(h1, off);
    if (t == 0) out[g] = h1 + rb2[0];
  }
}

// ================================================================ launch
extern "C" void kernel_launch(void* const* d_in, const int* in_sizes, int n_in,
                              void* d_out, int out_size, void* d_ws, size_t ws_size,
                              hipStream_t stream) {
  const float* x     = (const float*)d_in[0];
  const int*   ei    = (const int*)d_in[1];
  const int*   src   = ei;
  const int*   dst   = ei + N_EDGES;
  const int*   batch = (const int*)d_in[2];
  const float* Wl0   = (const float*)d_in[3];
  const float* Wr0   = (const float*)d_in[4];
  const float* Wl    = (const float*)d_in[6];
  const float* Wr    = (const float*)d_in[7];
  const float* gamma = (const float*)d_in[9];
  const float* beta  = (const float*)d_in[10];
  const float* rW1   = (const float*)d_in[11];
  const float* rb1   = (const float*)d_in[12];
  const float* rW2   = (const float*)d_in[13];
  const float* rb2   = (const float*)d_in[14];
  float* out = (float*)d_out;

  char* ws = (char*)d_ws;
  size_t off = 0;
  auto alloc = [&](size_t bytes) -> void* {
    void* p = ws + off;
    off = (off + bytes + 255) & ~(size_t)255;
    return p;
  };
  uint_t*   xb    = (uint_t*)alloc((size_t)N_NODES * 20 * 4);
  ushort_t* Pa    = (ushort_t*)alloc((size_t)N_NODES * 128 * 2);
  ushort_t* Pb    = (ushort_t*)alloc((size_t)N_NODES * 128 * 2);
  ushort_t* WT0   = (ushort_t*)alloc((size_t)128 * 96 * 2);
  ushort_t* WT1   = (ushort_t*)alloc((size_t)128 * 256 * 2);
  ushort_t* WT2   = (ushort_t*)alloc((size_t)128 * 256 * 2);
  float* invdeg = (float*)alloc((size_t)N_NODES * 4);
  int*   degi   = (int*)alloc((size_t)N_NODES * 4);
  int*   rowptr = (int*)alloc((size_t)(N_NODES + 1) * 4);
  int*   cursor = (int*)alloc((size_t)N_NODES * 4);
  ushort_t* colidx = (ushort_t*)alloc((size_t)N_EDGES * 2);
  int*   partial= (int*)alloc((size_t)N_NODES * 4);
  int*   bsum   = (int*)alloc(256 * 4);
  float* stats  = (float*)alloc(768 * 4);  // 3 layers x {sum[128],sumsq[128]}

  const int NB_SCAN = (N_NODES + 255) / 256;  // 196
  const int gemm_blocks = (N_NODES + 63) / 64;
  const int PREP_TOTAL = WP0 + 2 * WP1 + N_NODES * 20;
  const int PREP_BLOCKS = (PREP_TOTAL + 255) / 256;
  const int HIST_BLOCKS = 512;

  // ---- prep (weights/xb/stats) + histogram in one launch
  hipMemsetAsync(degi, 0, (size_t)N_NODES * 4, stream);
  prep_hist_kernel<<<PREP_BLOCKS + HIST_BLOCKS, 256, 0, stream>>>(
      Wl0, Wr0, Wl, Wr, x, dst, WT0, WT1, WT2, xb, stats, degi, PREP_BLOCKS);

  // ---- CSR build
  scan_block_kernel<<<NB_SCAN, 256, 0, stream>>>(degi, partial, bsum, invdeg);
  scan_add_fused_kernel<<<NB_SCAN + 1, 256, 0, stream>>>(partial, bsum, rowptr,
                                                         cursor, NB_SCAN);
  fill_sharded_kernel<<<2048, 256, 0, stream>>>(src, dst, cursor, colidx);

  // ---- layer 0 (fused gather + GEMM)
  gemm0_fused_kernel<<<gemm_blocks, 256, 0, stream>>>(xb, rowptr, colidx, invdeg,
                                                      WT0, Pa, stats);

  // ---- layer 1: Pa -> Pb
  gemm_fused_kernel<<<gemm_blocks, 256, 0, stream>>>(
      Pa, stats, gamma, beta, rowptr, colidx, invdeg, WT1, Pb, stats + 256);

  // ---- layer 2: Pb -> Pa
  gemm_fused_kernel<<<gemm_blocks, 256, 0, stream>>>(
      Pb, stats + 256, gamma + 128, beta + 128, rowptr, colidx, invdeg, WT2,
      Pa, stats + 512);

  // ---- fused global mean pool (final BN inline) + readout
  pool_readout_kernel<<<N_GRAPHS, 128, 0, stream>>>(
      Pa, stats + 512, gamma + 256, beta + 256, batch, rW1, rb1, rW2, rb2, out);
}

// Round 16
// 360.666 us; speedup vs baseline: 1.0709x; 1.0148x over previous
//
#include <hip/hip_runtime.h>

#define N_NODES 50000
#define N_EDGES 800000
#define N_GRAPHS 2000
#define BN_EPS 1e-5f
#define FSHARD 12500  // fill: N_NODES / 4

typedef unsigned short ushort_t;
typedef unsigned int uint_t;
typedef unsigned char uchar_t;
using bf16x8 = __attribute__((ext_vector_type(8))) short;
using f32x4  = __attribute__((ext_vector_type(4))) float;
using vf2    = __attribute__((ext_vector_type(2))) float;

__device__ inline float bf_lo(uint_t u) { return __uint_as_float(u << 16); }
__device__ inline float bf_hi(uint_t u) { return __uint_as_float(u & 0xffff0000u); }
__device__ inline ushort_t f2bf(float f) {  // round-to-nearest-even
  uint_t u = __float_as_uint(f);
  return (ushort_t)((u + 0x7fffu + ((u >> 16) & 1u)) >> 16);
}
__device__ inline uint_t pack2(float a, float b) {
  return (uint_t)f2bf(a) | ((uint_t)f2bf(b) << 16);
}
__device__ inline uchar_t f2fp8(float f) {  // OCP e4m3, RNE via HW cvt
  int pk = __builtin_amdgcn_cvt_pk_fp8_f32(f, f, 0, false);
  return (uchar_t)(pk & 0xff);
}

// ================================================================ CSR build
__global__ void fill_sharded_kernel(const int* __restrict__ src,
                                    const int* __restrict__ dst,
                                    int* __restrict__ cursor,
                                    ushort_t* __restrict__ col) {
  const int shard = blockIdx.x & 3;
  const int lo = shard * FSHARD, hi = lo + FSHARD;
  const int nb = gridDim.x >> 2, blk = blockIdx.x >> 2;
  for (int e = blk * blockDim.x + threadIdx.x; e < N_EDGES;
       e += nb * blockDim.x) {
    int d = dst[e];
    if (d >= lo && d < hi) {
      int p = atomicAdd(&cursor[d], 1);
      col[p] = (ushort_t)src[e];
    }
  }
}

__global__ void scan_block_kernel(const int* __restrict__ degi,
                                  int* __restrict__ partial,
                                  int* __restrict__ bsum,
                                  float* __restrict__ invdeg) {
  __shared__ int buf[2][256];
  int i = blockIdx.x * 256 + threadIdx.x;
  int v = (i < N_NODES) ? degi[i] : 0;
  buf[0][threadIdx.x] = v;
  __syncthreads();
  int pi = 0;
  for (int off = 1; off < 256; off <<= 1) {
    int nv = buf[pi][threadIdx.x];
    if (threadIdx.x >= off) nv += buf[pi][threadIdx.x - off];
    buf[pi ^ 1][threadIdx.x] = nv;
    pi ^= 1;
    __syncthreads();
  }
  int incl = buf[pi][threadIdx.x];
  if (i < N_NODES) {
    partial[i] = incl - v;
    invdeg[i] = 1.0f / fmaxf((float)v, 1.0f);
  }
  if (threadIdx.x == 255) bsum[blockIdx.x] = incl;
}

__global__ void scan_add_fused_kernel(const int* __restrict__ partial,
                                      const int* __restrict__ bsum,
                                      int* __restrict__ rowptr,
                                      int* __restrict__ cursor, int nb) {
  __shared__ int buf[2][256];
  __shared__ int sx[256];
  int t = threadIdx.x;
  int v = (t < nb) ? bsum[t] : 0;
  buf[0][t] = v;
  __syncthreads();
  int pi = 0;
  for (int off = 1; off < 256; off <<= 1) {
    int nv = buf[pi][t];
    if (t >= off) nv += buf[pi][t - off];
    buf[pi ^ 1][t] = nv;
    pi ^= 1;
    __syncthreads();
  }
  sx[t] = buf[pi][t] - v;
  __syncthreads();
  int add = sx[blockIdx.x];
  int i = blockIdx.x * 256 + t;
  if (i < N_NODES) {
    int r = partial[i] + add;
    rowptr[i] = r;
    cursor[i] = r;
  } else if (i == N_NODES) {
    rowptr[N_NODES] = N_EDGES;
  }
}

// ================================================================ prep + hist (one launch)
#define WP0 (128 * 96)
#define WP1 (128 * 256)
__global__ void prep_hist_kernel(const float* __restrict__ Wl0,
                                 const float* __restrict__ Wr0,
                                 const float* __restrict__ Wl,
                                 const float* __restrict__ Wr,
                                 const float* __restrict__ x,
                                 const int* __restrict__ dst,
                                 ushort_t* __restrict__ WT0,
                                 ushort_t* __restrict__ WT1,
                                 ushort_t* __restrict__ WT2,
                                 uint_t* __restrict__ xb,
                                 float* __restrict__ stats,
                                 int* __restrict__ degi, int prep_blocks) {
  if ((int)blockIdx.x >= prep_blocks) {
    const int nb = gridDim.x - prep_blocks;
    const int blk = blockIdx.x - prep_blocks;
    for (int e = blk * blockDim.x + threadIdx.x; e < N_EDGES;
         e += nb * blockDim.x)
      atomicAdd(&degi[dst[e]], 1);
    return;
  }
  int idx = blockIdx.x * blockDim.x + threadIdx.x;
  if (idx < 768) stats[idx] = 0.f;
  if (idx < WP0) {
    int c = idx / 96, k = idx - c * 96;
    float v = 0.f;
    if (k < 38) v = Wl0[k * 128 + c];
    else if (k < 76) v = Wr0[(k - 38) * 128 + c];
    WT0[(k >> 5) * 4096 + c * 32 + (k & 31)] = f2bf(v);
  } else if (idx < WP0 + 2 * WP1) {
    int i2 = idx - WP0;
    int layer = i2 / WP1;
    int j = i2 - layer * WP1;
    int c = j / 256, k = j - c * 256;
    const float* L = Wl + layer * 16384;
    const float* R = Wr + layer * 16384;
    float v = (k < 128) ? L[k * 128 + c] : R[(k - 128) * 128 + c];
    ushort_t* W = layer ? WT2 : WT1;
    W[(k >> 5) * 4096 + c * 32 + (k & 31)] = f2bf(v);
  } else if (idx < WP0 + 2 * WP1 + N_NODES * 20) {
    int j = idx - (WP0 + 2 * WP1);
    int row = j / 20, c2 = (j - row * 20) * 2;
    float v0 = (c2 < 38) ? x[row * 38 + c2] : 0.f;
    float v1 = (c2 + 1 < 38) ? x[row * 38 + c2 + 1] : 0.f;
    xb[j] = pack2(v0, v1);
  }
}

// ================================================================ layer-0 fused
// Gather: 2 nodes/wave, lanes 0..18 own col-pairs, 4-deep unroll.
// Writes P (bf16, pre-BN) and Hq (fp8 e4m3 pre-BN, for layer-1 gather).
__global__ __launch_bounds__(256, 6) void gemm0_fused_kernel(
    const uint_t* __restrict__ xb, const int* __restrict__ rowptr,
    const ushort_t* __restrict__ col, const float* __restrict__ invdeg,
    const ushort_t* __restrict__ WT, ushort_t* __restrict__ P,
    uchar_t* __restrict__ Hq, float* __restrict__ stats) {
  __shared__ __align__(16) uint_t aggA[64 * 52];  // 64 rows x 96 bf16 + pad
  __shared__ __align__(16) ushort_t sB[128 * 40];
  const int tid = threadIdx.x;
  const int row0 = blockIdx.x * 64;
  const int w = tid >> 6;
  const int l = tid & 63;

  // ---- gather phase
  {
    int half = l >> 5;
    int j = l & 31;
    for (int pass = 0; pass < 8; pass++) {
      int r = w * 16 + pass * 2 + half;
      int node = row0 + r;
      if (j < 19) {
        uint_t o = 0;
        if (node < N_NODES) {
          int beg = rowptr[node], end = rowptr[node + 1];
          float a0 = 0.f, a1 = 0.f;
          int e = beg;
          for (; e + 3 < end; e += 4) {
            uint_t u0 = xb[(size_t)col[e] * 20 + j];
            uint_t u1 = xb[(size_t)col[e + 1] * 20 + j];
            uint_t u2 = xb[(size_t)col[e + 2] * 20 + j];
            uint_t u3 = xb[(size_t)col[e + 3] * 20 + j];
            a0 += (bf_lo(u0) + bf_lo(u1)) + (bf_lo(u2) + bf_lo(u3));
            a1 += (bf_hi(u0) + bf_hi(u1)) + (bf_hi(u2) + bf_hi(u3));
          }
          for (; e < end; e++) {
            uint_t u = xb[(size_t)col[e] * 20 + j];
            a0 += bf_lo(u);
            a1 += bf_hi(u);
          }
          float inv = invdeg[node];
          o = pack2(a0 * inv, a1 * inv);
        }
        aggA[r * 52 + j] = o;
      }
    }
  }
  // ---- self + zero fill: uints 19..47 of each row
  for (int idx = tid; idx < 64 * 29; idx += 256) {
    int r = idx / 29;
    int j2 = idx - r * 29 + 19;
    int node = row0 + r;
    uint_t v = 0;
    if (node < N_NODES && j2 < 38) v = xb[(size_t)node * 20 + (j2 - 19)];
    aggA[r * 52 + j2] = v;
  }

  // ---- K loop (Kc = 96)
  const int m = l & 15;
  const int quad = l >> 4;
  f32x4 acc[8];
#pragma unroll
  for (int ct = 0; ct < 8; ct++) acc[ct] = (f32x4){0.f, 0.f, 0.f, 0.f};

  for (int kk = 0; kk < 96; kk += 32) {
    __syncthreads();
    {
      const uint4* wp = (const uint4*)(WT + (kk >> 5) * 4096);
      uint4 v0 = wp[tid];
      uint4 v1 = wp[tid + 256];
      *((uint4*)&sB[(tid >> 2) * 40 + (tid & 3) * 8]) = v0;
      int t2 = tid + 256;
      *((uint4*)&sB[(t2 >> 2) * 40 + (t2 & 3) * 8]) = v1;
    }
    __syncthreads();
    bf16x8 a = *(const bf16x8*)((const ushort_t*)aggA + (w * 16 + m) * 104 +
                                kk + quad * 8);
#pragma unroll
    for (int ct = 0; ct < 8; ct++) {
      bf16x8 b = *(const bf16x8*)&sB[(ct * 16 + m) * 40 + quad * 8];
      acc[ct] = __builtin_amdgcn_mfma_f32_16x16x32_bf16(a, b, acc[ct], 0, 0, 0);
    }
  }

#pragma unroll
  for (int ct = 0; ct < 8; ct++) {
#pragma unroll
    for (int v = 0; v < 4; v++) {
      int row = row0 + w * 16 + quad * 4 + v;
      if (row < N_NODES) {
        P[(size_t)row * 128 + ct * 16 + m] = f2bf(acc[ct][v]);
        Hq[(size_t)row * 128 + ct * 16 + m] = f2fp8(acc[ct][v]);
      }
    }
  }

  float* red = (float*)sB;
  __syncthreads();
#pragma unroll
  for (int ct = 0; ct < 8; ct++) {
    float s = 0.f, q = 0.f;
#pragma unroll
    for (int v = 0; v < 4; v++) {
      s += acc[ct][v];
      q += acc[ct][v] * acc[ct][v];
    }
    float t;
    t = __shfl_xor(s, 16); s += t;
    t = __shfl_xor(s, 32); s += t;
    t = __shfl_xor(q, 16); q += t;
    t = __shfl_xor(q, 32); q += t;
    if (l < 16) {
      red[w * 256 + ct * 16 + l] = s;
      red[w * 256 + 128 + ct * 16 + l] = q;
    }
  }
  __syncthreads();
  if (tid < 128) {
    float s = 0.f, q = 0.f;
#pragma unroll
    for (int wv = 0; wv < 4; wv++) {
      s += red[wv * 256 + tid];
      q += red[wv * 256 + 128 + tid];
    }
    atomicAdd(&stats[tid], s);
    atomicAdd(&stats[128 + tid], q);
  }
}

// ================================================================ fused layer kernel
// Gather reads fp8 rows (128 B vs 256 B bf16) + HW decode; BN+ReLU on the
// fly. Self path (k>=128) stays bf16 via sA staging. Writes Pout (bf16)
// + Hout (fp8) + stats.
__global__ __launch_bounds__(256, 4) void gemm_fused_kernel(
    const ushort_t* __restrict__ Pin, const uchar_t* __restrict__ Hin,
    const float* __restrict__ stats_prev,
    const float* __restrict__ gamma, const float* __restrict__ beta,
    const int* __restrict__ rowptr, const ushort_t* __restrict__ col,
    const float* __restrict__ invdeg, const ushort_t* __restrict__ WT,
    ushort_t* __restrict__ Pout, uchar_t* __restrict__ Hout,
    float* __restrict__ stats_out) {
  __shared__ __align__(16) uint_t aggu[64 * 68];
  __shared__ __align__(16) ushort_t sA[64 * 40];
  __shared__ __align__(16) ushort_t sB[128 * 40];
  __shared__ float ssc[256];
  const int tid = threadIdx.x;
  const int row0 = blockIdx.x * 64;

  if (tid < 128) {
    const float invN = 1.0f / (float)N_NODES;
    float mean = stats_prev[tid] * invN;
    float var = stats_prev[128 + tid] * invN - mean * mean;
    float scale = gamma[tid] * rsqrtf(var + BN_EPS);
    ssc[tid] = scale;
    ssc[128 + tid] = beta[tid] - mean * scale;
  }
  __syncthreads();

  const int w = tid >> 6;
  const int g2 = (tid >> 4) & 3;
  const int h = tid & 15;
  const uint2* Hu = (const uint2*)Hin;  // row stride 16 uint2 (128 B)
  {
    int c0 = h * 8;
    float s[8], b[8];
#pragma unroll
    for (int j = 0; j < 8; j++) {
      s[j] = ssc[c0 + j];
      b[j] = ssc[128 + c0 + j];
    }
    for (int pass = 0; pass < 4; pass++) {
      int r = w * 16 + pass * 4 + g2;
      int node = row0 + r;
      uint4 o = make_uint4(0, 0, 0, 0);
      if (node < N_NODES) {
        int beg = rowptr[node], end = rowptr[node + 1];
        float a[8];
#pragma unroll
        for (int j = 0; j < 8; j++) a[j] = 0.f;
        int e = beg;
        for (; e + 3 < end; e += 4) {
          uint2 u0 = Hu[(size_t)col[e] * 16 + h];
          uint2 u1 = Hu[(size_t)col[e + 1] * 16 + h];
          uint2 u2 = Hu[(size_t)col[e + 2] * 16 + h];
          uint2 u3 = Hu[(size_t)col[e + 3] * 16 + h];
          uint2 uu[4] = {u0, u1, u2, u3};
#pragma unroll
          for (int q4 = 0; q4 < 4; q4++) {
            vf2 f01 = __builtin_amdgcn_cvt_pk_f32_fp8((int)uu[q4].x, false);
            vf2 f23 = __builtin_amdgcn_cvt_pk_f32_fp8((int)uu[q4].x, true);
            vf2 f45 = __builtin_amdgcn_cvt_pk_f32_fp8((int)uu[q4].y, false);
            vf2 f67 = __builtin_amdgcn_cvt_pk_f32_fp8((int)uu[q4].y, true);
            a[0] += fmaxf(f01[0] * s[0] + b[0], 0.f);
            a[1] += fmaxf(f01[1] * s[1] + b[1], 0.f);
            a[2] += fmaxf(f23[0] * s[2] + b[2], 0.f);
            a[3] += fmaxf(f23[1] * s[3] + b[3], 0.f);
            a[4] += fmaxf(f45[0] * s[4] + b[4], 0.f);
            a[5] += fmaxf(f45[1] * s[5] + b[5], 0.f);
            a[6] += fmaxf(f67[0] * s[6] + b[6], 0.f);
            a[7] += fmaxf(f67[1] * s[7] + b[7], 0.f);
          }
        }
        for (; e < end; e++) {
          uint2 u = Hu[(size_t)col[e] * 16 + h];
          vf2 f01 = __builtin_amdgcn_cvt_pk_f32_fp8((int)u.x, false);
          vf2 f23 = __builtin_amdgcn_cvt_pk_f32_fp8((int)u.x, true);
          vf2 f45 = __builtin_amdgcn_cvt_pk_f32_fp8((int)u.y, false);
          vf2 f67 = __builtin_amdgcn_cvt_pk_f32_fp8((int)u.y, true);
          a[0] += fmaxf(f01[0] * s[0] + b[0], 0.f);
          a[1] += fmaxf(f01[1] * s[1] + b[1], 0.f);
          a[2] += fmaxf(f23[0] * s[2] + b[2], 0.f);
          a[3] += fmaxf(f23[1] * s[3] + b[3], 0.f);
          a[4] += fmaxf(f45[0] * s[4] + b[4], 0.f);
          a[5] += fmaxf(f45[1] * s[5] + b[5], 0.f);
          a[6] += fmaxf(f67[0] * s[6] + b[6], 0.f);
          a[7] += fmaxf(f67[1] * s[7] + b[7], 0.f);
        }
        float inv = invdeg[node];
        o.x = pack2(a[0] * inv, a[1] * inv);
        o.y = pack2(a[2] * inv, a[3] * inv);
        o.z = pack2(a[4] * inv, a[5] * inv);
        o.w = pack2(a[6] * inv, a[7] * inv);
      }
      *((uint4*)&aggu[r * 68 + h * 4]) = o;
    }
  }
  __syncthreads();

  const int l = tid & 63;
  const int m = l & 15;
  const int quad = l >> 4;
  f32x4 acc[8];
#pragma unroll
  for (int ct = 0; ct < 8; ct++) acc[ct] = (f32x4){0.f, 0.f, 0.f, 0.f};

  for (int kk = 0; kk < 256; kk += 32) {
    __syncthreads();
    {
      const uint4* wp = (const uint4*)(WT + (kk >> 5) * 4096);
      uint4 v0 = wp[tid];
      uint4 v1 = wp[tid + 256];
      *((uint4*)&sB[(tid >> 2) * 40 + (tid & 3) * 8]) = v0;
      int t2 = tid + 256;
      *((uint4*)&sB[(t2 >> 2) * 40 + (t2 & 3) * 8]) = v1;
    }
    if (kk >= 128) {
      int r = tid >> 2, c = tid & 3;
      int row = row0 + r;
      uint4 v = make_uint4(0, 0, 0, 0);
      if (row < N_NODES) {
        int pcol = kk - 128 + c * 8;
        uint4 u = *(const uint4*)(Pin + (size_t)row * 128 + pcol);
        uint_t in[4] = {u.x, u.y, u.z, u.w};
        uint_t ov[4];
#pragma unroll
        for (int p = 0; p < 4; p++) {
          int cc = pcol + 2 * p;
          float f0 = fmaxf(bf_lo(in[p]) * ssc[cc] + ssc[128 + cc], 0.f);
          float f1 = fmaxf(bf_hi(in[p]) * ssc[cc + 1] + ssc[128 + cc + 1], 0.f);
          ov[p] = pack2(f0, f1);
        }
        v = make_uint4(ov[0], ov[1], ov[2], ov[3]);
      }
      *((uint4*)&sA[r * 40 + c * 8]) = v;
    }
    __syncthreads();
    bf16x8 a;
    if (kk < 128)
      a = *(const bf16x8*)((const ushort_t*)aggu + (w * 16 + m) * 136 + kk + quad * 8);
    else
      a = *(const bf16x8*)&sA[(w * 16 + m) * 40 + quad * 8];
#pragma unroll
    for (int ct = 0; ct < 8; ct++) {
      bf16x8 bb = *(const bf16x8*)&sB[(ct * 16 + m) * 40 + quad * 8];
      acc[ct] = __builtin_amdgcn_mfma_f32_16x16x32_bf16(a, bb, acc[ct], 0, 0, 0);
    }
  }

#pragma unroll
  for (int ct = 0; ct < 8; ct++) {
#pragma unroll
    for (int v = 0; v < 4; v++) {
      int row = row0 + w * 16 + quad * 4 + v;
      if (row < N_NODES) {
        Pout[(size_t)row * 128 + ct * 16 + m] = f2bf(acc[ct][v]);
        Hout[(size_t)row * 128 + ct * 16 + m] = f2fp8(acc[ct][v]);
      }
    }
  }

  float* red = (float*)sA;
  __syncthreads();
#pragma unroll
  for (int ct = 0; ct < 8; ct++) {
    float ss = 0.f, q = 0.f;
#pragma unroll
    for (int v = 0; v < 4; v++) {
      ss += acc[ct][v];
      q += acc[ct][v] * acc[ct][v];
    }
    float t;
    t = __shfl_xor(ss, 16); ss += t;
    t = __shfl_xor(ss, 32); ss += t;
    t = __shfl_xor(q, 16); q += t;
    t = __shfl_xor(q, 32); q += t;
    if (l < 16) {
      red[w * 256 + ct * 16 + l] = ss;
      red[w * 256 + 128 + ct * 16 + l] = q;
    }
  }
  __syncthreads();
  if (tid < 128) {
    float ss = 0.f, q = 0.f;
#pragma unroll
    for (int wv = 0; wv < 4; wv++) {
      ss += red[wv * 256 + tid];
      q += red[wv * 256 + 128 + tid];
    }
    atomicAdd(&stats_out[tid], ss);
    atomicAdd(&stats_out[128 + tid], q);
  }
}

// ================================================================ pool + readout
__global__ __launch_bounds__(128) void pool_readout_kernel(
    const ushort_t* __restrict__ P, const float* __restrict__ stats,
    const float* __restrict__ gamma, const float* __restrict__ beta,
    const int* __restrict__ batch, const float* __restrict__ rW1,
    const float* __restrict__ rb1, const float* __restrict__ rW2,
    const float* __restrict__ rb2, float* __restrict__ out) {
  int g = blockIdx.x;
  int t = threadIdx.x;
  int lo = 0, hi = N_NODES;
  while (lo < hi) { int mid = (lo + hi) >> 1; if (batch[mid] < g) lo = mid + 1; else hi = mid; }
  int gs = lo;
  hi = N_NODES;
  while (lo < hi) { int mid = (lo + hi) >> 1; if (batch[mid] < g + 1) lo = mid + 1; else hi = mid; }
  int ge = lo;
  const float invN = 1.0f / (float)N_NODES;
  float mean = stats[t] * invN;
  float var = stats[128 + t] * invN - mean * mean;
  float s = gamma[t] * rsqrtf(var + BN_EPS);
  float b = beta[t] - mean * s;
  float acc = 0.f;
  const ushort_t* pr = P + (size_t)gs * 128 + t;
  for (int r = gs; r < ge; r++, pr += 128)
    acc += fmaxf(__uint_as_float(((uint_t)*pr) << 16) * s + b, 0.f);
  __shared__ float pl[128];
  pl[t] = acc / fmaxf((float)(ge - gs), 1.f);
  __syncthreads();
  if (t < 64) {
    float h1 = rb1[t];
    for (int k = 0; k < 128; k++) h1 += pl[k] * rW1[k * 64 + t];
    h1 = fmaxf(h1, 0.f) * rW2[t];
#pragma unroll
    for (int off = 32; off > 0; off >>= 1) h1 += __shfl_down(h1, off);
    if (t == 0) out[g] = h1 + rb2[0];
  }
}

// ================================================================ launch
extern "C" void kernel_launch(void* const* d_in, const int* in_sizes, int n_in,
                              void* d_out, int out_size, void* d_ws, size_t ws_size,
                              hipStream_t stream) {
  const float* x     = (const float*)d_in[0];
  const int*   ei    = (const int*)d_in[1];
  const int*   src   = ei;
  const int*   dst   = ei + N_EDGES;
  const int*   batch = (const int*)d_in[2];
  const float* Wl0   = (const float*)d_in[3];
  const float* Wr0   = (const float*)d_in[4];
  const float* Wl    = (const float*)d_in[6];
  const float* Wr    = (const float*)d_in[7];
  const float* gamma = (const float*)d_in[9];
  const float* beta  = (const float*)d_in[10];
  const float* rW1   = (const float*)d_in[11];
  const float* rb1   = (const float*)d_in[12];
  const float* rW2   = (const float*)d_in[13];
  const float* rb2   = (const float*)d_in[14];
  float* out = (float*)d_out;

  char* ws = (char*)d_ws;
  size_t off = 0;
  auto alloc = [&](size_t bytes) -> void* {
    void* p = ws + off;
    off = (off + bytes + 255) & ~(size_t)255;
    return p;
  };
  uint_t*   xb    = (uint_t*)alloc((size_t)N_NODES * 20 * 4);
  ushort_t* Pa    = (ushort_t*)alloc((size_t)N_NODES * 128 * 2);
  ushort_t* Pb    = (ushort_t*)alloc((size_t)N_NODES * 128 * 2);
  uchar_t*  Ha    = (uchar_t*)alloc((size_t)N_NODES * 128);
  uchar_t*  Hb    = (uchar_t*)alloc((size_t)N_NODES * 128);
  ushort_t* WT0   = (ushort_t*)alloc((size_t)128 * 96 * 2);
  ushort_t* WT1   = (ushort_t*)alloc((size_t)128 * 256 * 2);
  ushort_t* WT2   = (ushort_t*)alloc((size_t)128 * 256 * 2);
  float* invdeg = (float*)alloc((size_t)N_NODES * 4);
  int*   degi   = (int*)alloc((size_t)N_NODES * 4);
  int*   rowptr = (int*)alloc((size_t)(N_NODES + 1) * 4);
  int*   cursor = (int*)alloc((size_t)N_NODES * 4);
  ushort_t* colidx = (ushort_t*)alloc((size_t)N_EDGES * 2);
  int*   partial= (int*)alloc((size_t)N_NODES * 4);
  int*   bsum   = (int*)alloc(256 * 4);
  float* stats  = (float*)alloc(768 * 4);  // 3 layers x {sum[128],sumsq[128]}

  const int NB_SCAN = (N_NODES + 255) / 256;  // 196
  const int gemm_blocks = (N_NODES + 63) / 64;
  const int PREP_TOTAL = WP0 + 2 * WP1 + N_NODES * 20;
  const int PREP_BLOCKS = (PREP_TOTAL + 255) / 256;
  const int HIST_BLOCKS = 512;

  // ---- prep (weights/xb/stats) + histogram in one launch
  hipMemsetAsync(degi, 0, (size_t)N_NODES * 4, stream);
  prep_hist_kernel<<<PREP_BLOCKS + HIST_BLOCKS, 256, 0, stream>>>(
      Wl0, Wr0, Wl, Wr, x, dst, WT0, WT1, WT2, xb, stats, degi, PREP_BLOCKS);

  // ---- CSR build
  scan_block_kernel<<<NB_SCAN, 256, 0, stream>>>(degi, partial, bsum, invdeg);
  scan_add_fused_kernel<<<NB_SCAN + 1, 256, 0, stream>>>(partial, bsum, rowptr,
                                                         cursor, NB_SCAN);
  fill_sharded_kernel<<<2048, 256, 0, stream>>>(src, dst, cursor, colidx);

  // ---- layer 0 (fused gather + GEMM) -> Pa (bf16) + Ha (fp8)
  gemm0_fused_kernel<<<gemm_blocks, 256, 0, stream>>>(xb, rowptr, colidx, invdeg,
                                                      WT0, Pa, Ha, stats);

  // ---- layer 1: gather Ha (fp8), self Pa -> Pb + Hb
  gemm_fused_kernel<<<gemm_blocks, 256, 0, stream>>>(
      Pa, Ha, stats, gamma, beta, rowptr, colidx, invdeg, WT1, Pb, Hb,
      stats + 256);

  // ---- layer 2: gather Hb (fp8), self Pb -> Pa (+ Ha dummy)
  gemm_fused_kernel<<<gemm_blocks, 256, 0, stream>>>(
      Pb, Hb, stats + 256, gamma + 128, beta + 128, rowptr, colidx, invdeg,
      WT2, Pa, Ha, stats + 512);

  // ---- fused global mean pool (final BN inline) + readout
  pool_readout_kernel<<<N_GRAPHS, 128, 0, stream>>>(
      Pa, stats + 512, gamma + 256, beta + 256, batch, rW1, rb1, rW2, rb2, out);
}

// Round 17
// 359.488 us; speedup vs baseline: 1.0744x; 1.0033x over previous
//
#include <hip/hip_runtime.h>

#define N_NODES 50000
#define N_EDGES 800000
#define N_GRAPHS 2000
#define BN_EPS 1e-5f
#define FSHARD 12500  // fill: N_NODES / 4

typedef unsigned short ushort_t;
typedef unsigned int uint_t;
typedef unsigned char uchar_t;
using bf16x8 = __attribute__((ext_vector_type(8))) short;
using f32x4  = __attribute__((ext_vector_type(4))) float;
using vf2    = __attribute__((ext_vector_type(2))) float;

__device__ inline float bf_lo(uint_t u) { return __uint_as_float(u << 16); }
__device__ inline float bf_hi(uint_t u) { return __uint_as_float(u & 0xffff0000u); }
__device__ inline ushort_t f2bf(float f) {  // round-to-nearest-even
  uint_t u = __float_as_uint(f);
  return (ushort_t)((u + 0x7fffu + ((u >> 16) & 1u)) >> 16);
}
__device__ inline uint_t pack2(float a, float b) {
  return (uint_t)f2bf(a) | ((uint_t)f2bf(b) << 16);
}
__device__ inline uchar_t f2fp8(float f) {  // OCP e4m3, RNE via HW cvt
  int pk = __builtin_amdgcn_cvt_pk_fp8_f32(f, f, 0, false);
  return (uchar_t)(pk & 0xff);
}

// ================================================================ CSR build
__global__ void fill_sharded_kernel(const int* __restrict__ src,
                                    const int* __restrict__ dst,
                                    int* __restrict__ cursor,
                                    ushort_t* __restrict__ col) {
  const int shard = blockIdx.x & 3;
  const int lo = shard * FSHARD, hi = lo + FSHARD;
  const int nb = gridDim.x >> 2, blk = blockIdx.x >> 2;
  for (int e = blk * blockDim.x + threadIdx.x; e < N_EDGES;
       e += nb * blockDim.x) {
    int d = dst[e];
    if (d >= lo && d < hi) {
      int p = atomicAdd(&cursor[d], 1);
      col[p] = (ushort_t)src[e];
    }
  }
}

__global__ void scan_block_kernel(const int* __restrict__ degi,
                                  int* __restrict__ partial,
                                  int* __restrict__ bsum,
                                  float* __restrict__ invdeg) {
  __shared__ int buf[2][256];
  int i = blockIdx.x * 256 + threadIdx.x;
  int v = (i < N_NODES) ? degi[i] : 0;
  buf[0][threadIdx.x] = v;
  __syncthreads();
  int pi = 0;
  for (int off = 1; off < 256; off <<= 1) {
    int nv = buf[pi][threadIdx.x];
    if (threadIdx.x >= off) nv += buf[pi][threadIdx.x - off];
    buf[pi ^ 1][threadIdx.x] = nv;
    pi ^= 1;
    __syncthreads();
  }
  int incl = buf[pi][threadIdx.x];
  if (i < N_NODES) {
    partial[i] = incl - v;
    invdeg[i] = 1.0f / fmaxf((float)v, 1.0f);
  }
  if (threadIdx.x == 255) bsum[blockIdx.x] = incl;
}

__global__ void scan_add_fused_kernel(const int* __restrict__ partial,
                                      const int* __restrict__ bsum,
                                      int* __restrict__ rowptr,
                                      int* __restrict__ cursor, int nb) {
  __shared__ int buf[2][256];
  __shared__ int sx[256];
  int t = threadIdx.x;
  int v = (t < nb) ? bsum[t] : 0;
  buf[0][t] = v;
  __syncthreads();
  int pi = 0;
  for (int off = 1; off < 256; off <<= 1) {
    int nv = buf[pi][t];
    if (t >= off) nv += buf[pi][t - off];
    buf[pi ^ 1][t] = nv;
    pi ^= 1;
    __syncthreads();
  }
  sx[t] = buf[pi][t] - v;
  __syncthreads();
  int add = sx[blockIdx.x];
  int i = blockIdx.x * 256 + t;
  if (i < N_NODES) {
    int r = partial[i] + add;
    rowptr[i] = r;
    cursor[i] = r;
  } else if (i == N_NODES) {
    rowptr[N_NODES] = N_EDGES;
  }
}

// ================================================================ prep + hist (one launch)
#define WP0 (128 * 96)
#define WP1 (128 * 256)
__global__ void prep_hist_kernel(const float* __restrict__ Wl0,
                                 const float* __restrict__ Wr0,
                                 const float* __restrict__ Wl,
                                 const float* __restrict__ Wr,
                                 const float* __restrict__ x,
                                 const int* __restrict__ dst,
                                 ushort_t* __restrict__ WT0,
                                 ushort_t* __restrict__ WT1,
                                 ushort_t* __restrict__ WT2,
                                 uint_t* __restrict__ xb,
                                 float* __restrict__ stats,
                                 int* __restrict__ degi, int prep_blocks) {
  if ((int)blockIdx.x >= prep_blocks) {
    const int nb = gridDim.x - prep_blocks;
    const int blk = blockIdx.x - prep_blocks;
    for (int e = blk * blockDim.x + threadIdx.x; e < N_EDGES;
         e += nb * blockDim.x)
      atomicAdd(&degi[dst[e]], 1);
    return;
  }
  int idx = blockIdx.x * blockDim.x + threadIdx.x;
  if (idx < 768) stats[idx] = 0.f;
  if (idx < WP0) {
    int c = idx / 96, k = idx - c * 96;
    float v = 0.f;
    if (k < 38) v = Wl0[k * 128 + c];
    else if (k < 76) v = Wr0[(k - 38) * 128 + c];
    WT0[(k >> 5) * 4096 + c * 32 + (k & 31)] = f2bf(v);
  } else if (idx < WP0 + 2 * WP1) {
    int i2 = idx - WP0;
    int layer = i2 / WP1;
    int j = i2 - layer * WP1;
    int c = j / 256, k = j - c * 256;
    const float* L = Wl + layer * 16384;
    const float* R = Wr + layer * 16384;
    float v = (k < 128) ? L[k * 128 + c] : R[(k - 128) * 128 + c];
    ushort_t* W = layer ? WT2 : WT1;
    W[(k >> 5) * 4096 + c * 32 + (k & 31)] = f2bf(v);
  } else if (idx < WP0 + 2 * WP1 + N_NODES * 20) {
    int j = idx - (WP0 + 2 * WP1);
    int row = j / 20, c2 = (j - row * 20) * 2;
    float v0 = (c2 < 38) ? x[row * 38 + c2] : 0.f;
    float v1 = (c2 + 1 < 38) ? x[row * 38 + c2 + 1] : 0.f;
    xb[j] = pack2(v0, v1);
  }
}

// ================================================================ layer-0 fused
__global__ __launch_bounds__(256, 6) void gemm0_fused_kernel(
    const uint_t* __restrict__ xb, const int* __restrict__ rowptr,
    const ushort_t* __restrict__ col, const float* __restrict__ invdeg,
    const ushort_t* __restrict__ WT, ushort_t* __restrict__ P,
    uchar_t* __restrict__ Hq, float* __restrict__ stats) {
  __shared__ __align__(16) uint_t aggA[64 * 52];  // 64 rows x 96 bf16 + pad
  __shared__ __align__(16) ushort_t sB[128 * 40];
  const int tid = threadIdx.x;
  const int row0 = blockIdx.x * 64;
  const int w = tid >> 6;
  const int l = tid & 63;

  // ---- gather phase: 2 nodes per wave (32 lanes each), lanes 0..18 active
  {
    int half = l >> 5;
    int j = l & 31;
    for (int pass = 0; pass < 8; pass++) {
      int r = w * 16 + pass * 2 + half;
      int node = row0 + r;
      if (j < 19) {
        uint_t o = 0;
        if (node < N_NODES) {
          int beg = rowptr[node], end = rowptr[node + 1];
          float a0 = 0.f, a1 = 0.f;
          int e = beg;
          for (; e + 3 < end; e += 4) {
            uint_t u0 = xb[(size_t)col[e] * 20 + j];
            uint_t u1 = xb[(size_t)col[e + 1] * 20 + j];
            uint_t u2 = xb[(size_t)col[e + 2] * 20 + j];
            uint_t u3 = xb[(size_t)col[e + 3] * 20 + j];
            a0 += (bf_lo(u0) + bf_lo(u1)) + (bf_lo(u2) + bf_lo(u3));
            a1 += (bf_hi(u0) + bf_hi(u1)) + (bf_hi(u2) + bf_hi(u3));
          }
          for (; e < end; e++) {
            uint_t u = xb[(size_t)col[e] * 20 + j];
            a0 += bf_lo(u);
            a1 += bf_hi(u);
          }
          float inv = invdeg[node];
          o = pack2(a0 * inv, a1 * inv);
        }
        aggA[r * 52 + j] = o;
      }
    }
  }
  // ---- self + zero fill: uints 19..47 of each row
  for (int idx = tid; idx < 64 * 29; idx += 256) {
    int r = idx / 29;
    int j2 = idx - r * 29 + 19;
    int node = row0 + r;
    uint_t v = 0;
    if (node < N_NODES && j2 < 38) v = xb[(size_t)node * 20 + (j2 - 19)];
    aggA[r * 52 + j2] = v;
  }

  // ---- K loop (Kc = 96)
  const int m = l & 15;
  const int quad = l >> 4;
  f32x4 acc[8];
#pragma unroll
  for (int ct = 0; ct < 8; ct++) acc[ct] = (f32x4){0.f, 0.f, 0.f, 0.f};

  for (int kk = 0; kk < 96; kk += 32) {
    __syncthreads();
    {
      const uint4* wp = (const uint4*)(WT + (kk >> 5) * 4096);
      uint4 v0 = wp[tid];
      uint4 v1 = wp[tid + 256];
      *((uint4*)&sB[(tid >> 2) * 40 + (tid & 3) * 8]) = v0;
      int t2 = tid + 256;
      *((uint4*)&sB[(t2 >> 2) * 40 + (t2 & 3) * 8]) = v1;
    }
    __syncthreads();
    bf16x8 a = *(const bf16x8*)((const ushort_t*)aggA + (w * 16 + m) * 104 +
                                kk + quad * 8);
#pragma unroll
    for (int ct = 0; ct < 8; ct++) {
      bf16x8 b = *(const bf16x8*)&sB[(ct * 16 + m) * 40 + quad * 8];
      acc[ct] = __builtin_amdgcn_mfma_f32_16x16x32_bf16(a, b, acc[ct], 0, 0, 0);
    }
  }

#pragma unroll
  for (int ct = 0; ct < 8; ct++) {
#pragma unroll
    for (int v = 0; v < 4; v++) {
      int row = row0 + w * 16 + quad * 4 + v;
      if (row < N_NODES) {
        P[(size_t)row * 128 + ct * 16 + m] = f2bf(acc[ct][v]);
        Hq[(size_t)row * 128 + ct * 16 + m] = f2fp8(acc[ct][v]);
      }
    }
  }

  float* red = (float*)sB;
  __syncthreads();
#pragma unroll
  for (int ct = 0; ct < 8; ct++) {
    float s = 0.f, q = 0.f;
#pragma unroll
    for (int v = 0; v < 4; v++) {
      s += acc[ct][v];
      q += acc[ct][v] * acc[ct][v];
    }
    float t;
    t = __shfl_xor(s, 16); s += t;
    t = __shfl_xor(s, 32); s += t;
    t = __shfl_xor(q, 16); q += t;
    t = __shfl_xor(q, 32); q += t;
    if (l < 16) {
      red[w * 256 + ct * 16 + l] = s;
      red[w * 256 + 128 + ct * 16 + l] = q;
    }
  }
  __syncthreads();
  if (tid < 128) {
    float s = 0.f, q = 0.f;
#pragma unroll
    for (int wv = 0; wv < 4; wv++) {
      s += red[wv * 256 + tid];
      q += red[wv * 256 + 128 + tid];
    }
    atomicAdd(&stats[tid], s);
    atomicAdd(&stats[128 + tid], q);
  }
}

// ================================================================ fused layer kernel
// fp8 gather with 8-deep unroll: 8 independent uint2 row-segment loads in
// flight per lane (16 VGPRs — affordable only because rows are fp8).
__global__ __launch_bounds__(256, 4) void gemm_fused_kernel(
    const ushort_t* __restrict__ Pin, const uchar_t* __restrict__ Hin,
    const float* __restrict__ stats_prev,
    const float* __restrict__ gamma, const float* __restrict__ beta,
    const int* __restrict__ rowptr, const ushort_t* __restrict__ col,
    const float* __restrict__ invdeg, const ushort_t* __restrict__ WT,
    ushort_t* __restrict__ Pout, uchar_t* __restrict__ Hout,
    float* __restrict__ stats_out) {
  __shared__ __align__(16) uint_t aggu[64 * 68];
  __shared__ __align__(16) ushort_t sA[64 * 40];
  __shared__ __align__(16) ushort_t sB[128 * 40];
  __shared__ float ssc[256];
  const int tid = threadIdx.x;
  const int row0 = blockIdx.x * 64;

  if (tid < 128) {
    const float invN = 1.0f / (float)N_NODES;
    float mean = stats_prev[tid] * invN;
    float var = stats_prev[128 + tid] * invN - mean * mean;
    float scale = gamma[tid] * rsqrtf(var + BN_EPS);
    ssc[tid] = scale;
    ssc[128 + tid] = beta[tid] - mean * scale;
  }
  __syncthreads();

  const int w = tid >> 6;
  const int g2 = (tid >> 4) & 3;
  const int h = tid & 15;
  const uint2* Hu = (const uint2*)Hin;  // row stride 16 uint2 (128 B)
  {
    int c0 = h * 8;
    float s[8], b[8];
#pragma unroll
    for (int j = 0; j < 8; j++) {
      s[j] = ssc[c0 + j];
      b[j] = ssc[128 + c0 + j];
    }
    for (int pass = 0; pass < 4; pass++) {
      int r = w * 16 + pass * 4 + g2;
      int node = row0 + r;
      uint4 o = make_uint4(0, 0, 0, 0);
      if (node < N_NODES) {
        int beg = rowptr[node], end = rowptr[node + 1];
        float a[8];
#pragma unroll
        for (int j = 0; j < 8; j++) a[j] = 0.f;
        int e = beg;
        for (; e + 7 < end; e += 8) {
          uint2 u[8];
#pragma unroll
          for (int q8 = 0; q8 < 8; q8++)
            u[q8] = Hu[(size_t)col[e + q8] * 16 + h];
#pragma unroll
          for (int q8 = 0; q8 < 8; q8++) {
            vf2 f01 = __builtin_amdgcn_cvt_pk_f32_fp8((int)u[q8].x, false);
            vf2 f23 = __builtin_amdgcn_cvt_pk_f32_fp8((int)u[q8].x, true);
            vf2 f45 = __builtin_amdgcn_cvt_pk_f32_fp8((int)u[q8].y, false);
            vf2 f67 = __builtin_amdgcn_cvt_pk_f32_fp8((int)u[q8].y, true);
            a[0] += fmaxf(f01[0] * s[0] + b[0], 0.f);
            a[1] += fmaxf(f01[1] * s[1] + b[1], 0.f);
            a[2] += fmaxf(f23[0] * s[2] + b[2], 0.f);
            a[3] += fmaxf(f23[1] * s[3] + b[3], 0.f);
            a[4] += fmaxf(f45[0] * s[4] + b[4], 0.f);
            a[5] += fmaxf(f45[1] * s[5] + b[5], 0.f);
            a[6] += fmaxf(f67[0] * s[6] + b[6], 0.f);
            a[7] += fmaxf(f67[1] * s[7] + b[7], 0.f);
          }
        }
        for (; e + 3 < end; e += 4) {
          uint2 u[4];
#pragma unroll
          for (int q4 = 0; q4 < 4; q4++)
            u[q4] = Hu[(size_t)col[e + q4] * 16 + h];
#pragma unroll
          for (int q4 = 0; q4 < 4; q4++) {
            vf2 f01 = __builtin_amdgcn_cvt_pk_f32_fp8((int)u[q4].x, false);
            vf2 f23 = __builtin_amdgcn_cvt_pk_f32_fp8((int)u[q4].x, true);
            vf2 f45 = __builtin_amdgcn_cvt_pk_f32_fp8((int)u[q4].y, false);
            vf2 f67 = __builtin_amdgcn_cvt_pk_f32_fp8((int)u[q4].y, true);
            a[0] += fmaxf(f01[0] * s[0] + b[0], 0.f);
            a[1] += fmaxf(f01[1] * s[1] + b[1], 0.f);
            a[2] += fmaxf(f23[0] * s[2] + b[2], 0.f);
            a[3] += fmaxf(f23[1] * s[3] + b[3], 0.f);
            a[4] += fmaxf(f45[0] * s[4] + b[4], 0.f);
            a[5] += fmaxf(f45[1] * s[5] + b[5], 0.f);
            a[6] += fmaxf(f67[0] * s[6] + b[6], 0.f);
            a[7] += fmaxf(f67[1] * s[7] + b[7], 0.f);
          }
        }
        for (; e < end; e++) {
          uint2 u = Hu[(size_t)col[e] * 16 + h];
          vf2 f01 = __builtin_amdgcn_cvt_pk_f32_fp8((int)u.x, false);
          vf2 f23 = __builtin_amdgcn_cvt_pk_f32_fp8((int)u.x, true);
          vf2 f45 = __builtin_amdgcn_cvt_pk_f32_fp8((int)u.y, false);
          vf2 f67 = __builtin_amdgcn_cvt_pk_f32_fp8((int)u.y, true);
          a[0] += fmaxf(f01[0] * s[0] + b[0], 0.f);
          a[1] += fmaxf(f01[1] * s[1] + b[1], 0.f);
          a[2] += fmaxf(f23[0] * s[2] + b[2], 0.f);
          a[3] += fmaxf(f23[1] * s[3] + b[3], 0.f);
          a[4] += fmaxf(f45[0] * s[4] + b[4], 0.f);
          a[5] += fmaxf(f45[1] * s[5] + b[5], 0.f);
          a[6] += fmaxf(f67[0] * s[6] + b[6], 0.f);
          a[7] += fmaxf(f67[1] * s[7] + b[7], 0.f);
        }
        float inv = invdeg[node];
        o.x = pack2(a[0] * inv, a[1] * inv);
        o.y = pack2(a[2] * inv, a[3] * inv);
        o.z = pack2(a[4] * inv, a[5] * inv);
        o.w = pack2(a[6] * inv, a[7] * inv);
      }
      *((uint4*)&aggu[r * 68 + h * 4]) = o;
    }
  }
  __syncthreads();

  const int l = tid & 63;
  const int m = l & 15;
  const int quad = l >> 4;
  f32x4 acc[8];
#pragma unroll
  for (int ct = 0; ct < 8; ct++) acc[ct] = (f32x4){0.f, 0.f, 0.f, 0.f};

  for (int kk = 0; kk < 256; kk += 32) {
    __syncthreads();
    {
      const uint4* wp = (const uint4*)(WT + (kk >> 5) * 4096);
      uint4 v0 = wp[tid];
      uint4 v1 = wp[tid + 256];
      *((uint4*)&sB[(tid >> 2) * 40 + (tid & 3) * 8]) = v0;
      int t2 = tid + 256;
      *((uint4*)&sB[(t2 >> 2) * 40 + (t2 & 3) * 8]) = v1;
    }
    if (kk >= 128) {
      int r = tid >> 2, c = tid & 3;
      int row = row0 + r;
      uint4 v = make_uint4(0, 0, 0, 0);
      if (row < N_NODES) {
        int pcol = kk - 128 + c * 8;
        uint4 u = *(const uint4*)(Pin + (size_t)row * 128 + pcol);
        uint_t in[4] = {u.x, u.y, u.z, u.w};
        uint_t ov[4];
#pragma unroll
        for (int p = 0; p < 4; p++) {
          int cc = pcol + 2 * p;
          float f0 = fmaxf(bf_lo(in[p]) * ssc[cc] + ssc[128 + cc], 0.f);
          float f1 = fmaxf(bf_hi(in[p]) * ssc[cc + 1] + ssc[128 + cc + 1], 0.f);
          ov[p] = pack2(f0, f1);
        }
        v = make_uint4(ov[0], ov[1], ov[2], ov[3]);
      }
      *((uint4*)&sA[r * 40 + c * 8]) = v;
    }
    __syncthreads();
    bf16x8 a;
    if (kk < 128)
      a = *(const bf16x8*)((const ushort_t*)aggu + (w * 16 + m) * 136 + kk + quad * 8);
    else
      a = *(const bf16x8*)&sA[(w * 16 + m) * 40 + quad * 8];
#pragma unroll
    for (int ct = 0; ct < 8; ct++) {
      bf16x8 bb = *(const bf16x8*)&sB[(ct * 16 + m) * 40 + quad * 8];
      acc[ct] = __builtin_amdgcn_mfma_f32_16x16x32_bf16(a, bb, acc[ct], 0, 0, 0);
    }
  }

#pragma unroll
  for (int ct = 0; ct < 8; ct++) {
#pragma unroll
    for (int v = 0; v < 4; v++) {
      int row = row0 + w * 16 + quad * 4 + v;
      if (row < N_NODES) {
        Pout[(size_t)row * 128 + ct * 16 + m] = f2bf(acc[ct][v]);
        Hout[(size_t)row * 128 + ct * 16 + m] = f2fp8(acc[ct][v]);
      }
    }
  }

  float* red = (float*)sA;
  __syncthreads();
#pragma unroll
  for (int ct = 0; ct < 8; ct++) {
    float ss = 0.f, q = 0.f;
#pragma unroll
    for (int v = 0; v < 4; v++) {
      ss += acc[ct][v];
      q += acc[ct][v] * acc[ct][v];
    }
    float t;
    t = __shfl_xor(ss, 16); ss += t;
    t = __shfl_xor(ss, 32); ss += t;
    t = __shfl_xor(q, 16); q += t;
    t = __shfl_xor(q, 32); q += t;
    if (l < 16) {
      red[w * 256 + ct * 16 + l] = ss;
      red[w * 256 + 128 + ct * 16 + l] = q;
    }
  }
  __syncthreads();
  if (tid < 128) {
    float ss = 0.f, q = 0.f;
#pragma unroll
    for (int wv = 0; wv < 4; wv++) {
      ss += red[wv * 256 + tid];
      q += red[wv * 256 + 128 + tid];
    }
    atomicAdd(&stats_out[tid], ss);
    atomicAdd(&stats_out[128 + tid], q);
  }
}

// ================================================================ pool + readout
__global__ __launch_bounds__(128) void pool_readout_kernel(
    const ushort_t* __restrict__ P, const float* __restrict__ stats,
    const float* __restrict__ gamma, const float* __restrict__ beta,
    const int* __restrict__ batch, const float* __restrict__ rW1,
    const float* __restrict__ rb1, const float* __restrict__ rW2,
    const float* __restrict__ rb2, float* __restrict__ out) {
  int g = blockIdx.x;
  int t = threadIdx.x;
  int lo = 0, hi = N_NODES;
  while (lo < hi) { int mid = (lo + hi) >> 1; if (batch[mid] < g) lo = mid + 1; else hi = mid; }
  int gs = lo;
  hi = N_NODES;
  while (lo < hi) { int mid = (lo + hi) >> 1; if (batch[mid] < g + 1) lo = mid + 1; else hi = mid; }
  int ge = lo;
  const float invN = 1.0f / (float)N_NODES;
  float mean = stats[t] * invN;
  float var = stats[128 + t] * invN - mean * mean;
  float s = gamma[t] * rsqrtf(var + BN_EPS);
  float b = beta[t] - mean * s;
  float acc = 0.f;
  const ushort_t* pr = P + (size_t)gs * 128 + t;
  for (int r = gs; r < ge; r++, pr += 128)
    acc += fmaxf(__uint_as_float(((uint_t)*pr) << 16) * s + b, 0.f);
  __shared__ float pl[128];
  pl[t] = acc / fmaxf((float)(ge - gs), 1.f);
  __syncthreads();
  if (t < 64) {
    float h1 = rb1[t];
    for (int k = 0; k < 128; k++) h1 += pl[k] * rW1[k * 64 + t];
    h1 = fmaxf(h1, 0.f) * rW2[t];
#pragma unroll
    for (int off = 32; off > 0; off >>= 1) h1 += __shfl_down(h1, off);
    if (t == 0) out[g] = h1 + rb2[0];
  }
}

// ================================================================ launch
extern "C" void kernel_launch(void* const* d_in, const int* in_sizes, int n_in,
                              void* d_out, int out_size, void* d_ws, size_t ws_size,
                              hipStream_t stream) {
  const float* x     = (const float*)d_in[0];
  const int*   ei    = (const int*)d_in[1];
  const int*   src   = ei;
  const int*   dst   = ei + N_EDGES;
  const int*   batch = (const int*)d_in[2];
  const float* Wl0   = (const float*)d_in[3];
  const float* Wr0   = (const float*)d_in[4];
  const float* Wl    = (const float*)d_in[6];
  const float* Wr    = (const float*)d_in[7];
  const float* gamma = (const float*)d_in[9];
  const float* beta  = (const float*)d_in[10];
  const float* rW1   = (const float*)d_in[11];
  const float* rb1   = (const float*)d_in[12];
  const float* rW2   = (const float*)d_in[13];
  const float* rb2   = (const float*)d_in[14];
  float* out = (float*)d_out;

  char* ws = (char*)d_ws;
  size_t off = 0;
  auto alloc = [&](size_t bytes) -> void* {
    void* p = ws + off;
    off = (off + bytes + 255) & ~(size_t)255;
    return p;
  };
  uint_t*   xb    = (uint_t*)alloc((size_t)N_NODES * 20 * 4);
  ushort_t* Pa    = (ushort_t*)alloc((size_t)N_NODES * 128 * 2);
  ushort_t* Pb    = (ushort_t*)alloc((size_t)N_NODES * 128 * 2);
  uchar_t*  Ha    = (uchar_t*)alloc((size_t)N_NODES * 128);
  uchar_t*  Hb    = (uchar_t*)alloc((size_t)N_NODES * 128);
  ushort_t* WT0   = (ushort_t*)alloc((size_t)128 * 96 * 2);
  ushort_t* WT1   = (ushort_t*)alloc((size_t)128 * 256 * 2);
  ushort_t* WT2   = (ushort_t*)alloc((size_t)128 * 256 * 2);
  float* invdeg = (float*)alloc((size_t)N_NODES * 4);
  int*   degi   = (int*)alloc((size_t)N_NODES * 4);
  int*   rowptr = (int*)alloc((size_t)(N_NODES + 1) * 4);
  int*   cursor = (int*)alloc((size_t)N_NODES * 4);
  ushort_t* colidx = (ushort_t*)alloc((size_t)N_EDGES * 2);
  int*   partial= (int*)alloc((size_t)N_NODES * 4);
  int*   bsum   = (int*)alloc(256 * 4);
  float* stats  = (float*)alloc(768 * 4);  // 3 layers x {sum[128],sumsq[128]}

  const int NB_SCAN = (N_NODES + 255) / 256;  // 196
  const int gemm_blocks = (N_NODES + 63) / 64;
  const int PREP_TOTAL = WP0 + 2 * WP1 + N_NODES * 20;
  const int PREP_BLOCKS = (PREP_TOTAL + 255) / 256;
  const int HIST_BLOCKS = 512;

  // ---- prep (weights/xb/stats) + histogram in one launch
  hipMemsetAsync(degi, 0, (size_t)N_NODES * 4, stream);
  prep_hist_kernel<<<PREP_BLOCKS + HIST_BLOCKS, 256, 0, stream>>>(
      Wl0, Wr0, Wl, Wr, x, dst, WT0, WT1, WT2, xb, stats, degi, PREP_BLOCKS);

  // ---- CSR build
  scan_block_kernel<<<NB_SCAN, 256, 0, stream>>>(degi, partial, bsum, invdeg);
  scan_add_fused_kernel<<<NB_SCAN + 1, 256, 0, stream>>>(partial, bsum, rowptr,
                                                         cursor, NB_SCAN);
  fill_sharded_kernel<<<2048, 256, 0, stream>>>(src, dst, cursor, colidx);

  // ---- layer 0 (fused gather + GEMM) -> Pa (bf16) + Ha (fp8)
  gemm0_fused_kernel<<<gemm_blocks, 256, 0, stream>>>(xb, rowptr, colidx, invdeg,
                                                      WT0, Pa, Ha, stats);

  // ---- layer 1: gather Ha (fp8), self Pa -> Pb + Hb
  gemm_fused_kernel<<<gemm_blocks, 256, 0, stream>>>(
      Pa, Ha, stats, gamma, beta, rowptr, colidx, invdeg, WT1, Pb, Hb,
      stats + 256);

  // ---- layer 2: gather Hb (fp8), self Pb -> Pa (+ Ha dummy)
  gemm_fused_kernel<<<gemm_blocks, 256, 0, stream>>>(
      Pb, Hb, stats + 256, gamma + 128, beta + 128, rowptr, colidx, invdeg,
      WT2, Pa, Ha, stats + 512);

  // ---- fused global mean pool (final BN inline) + readout
  pool_readout_kernel<<<N_GRAPHS, 128, 0, stream>>>(
      Pa, stats + 512, gamma + 256, beta + 256, batch, rW1, rb1, rW2, rb2, out);
}

// Round 18
// 353.351 us; speedup vs baseline: 1.0931x; 1.0174x over previous
//
#include <hip/hip_runtime.h>

#define N_NODES 50000
#define N_EDGES 800000
#define N_GRAPHS 2000
#define BN_EPS 1e-5f
#define FSHARD 12500  // fill: N_NODES / 4

typedef unsigned short ushort_t;
typedef unsigned int uint_t;
typedef unsigned char uchar_t;
using bf16x8 = __attribute__((ext_vector_type(8))) short;
using f32x4  = __attribute__((ext_vector_type(4))) float;
using vf2    = __attribute__((ext_vector_type(2))) float;

__device__ inline float bf_lo(uint_t u) { return __uint_as_float(u << 16); }
__device__ inline float bf_hi(uint_t u) { return __uint_as_float(u & 0xffff0000u); }
__device__ inline ushort_t f2bf(float f) {  // round-to-nearest-even
  uint_t u = __float_as_uint(f);
  return (ushort_t)((u + 0x7fffu + ((u >> 16) & 1u)) >> 16);
}
__device__ inline uint_t pack2(float a, float b) {
  return (uint_t)f2bf(a) | ((uint_t)f2bf(b) << 16);
}
__device__ inline uchar_t f2fp8(float f) {  // OCP e4m3, RNE via HW cvt
  int pk = __builtin_amdgcn_cvt_pk_fp8_f32(f, f, 0, false);
  return (uchar_t)(pk & 0xff);
}

// ================================================================ CSR build
__global__ void fill_sharded_kernel(const int* __restrict__ src,
                                    const int* __restrict__ dst,
                                    int* __restrict__ cursor,
                                    ushort_t* __restrict__ col) {
  const int shard = blockIdx.x & 3;
  const int lo = shard * FSHARD, hi = lo + FSHARD;
  const int nb = gridDim.x >> 2, blk = blockIdx.x >> 2;
  for (int e = blk * blockDim.x + threadIdx.x; e < N_EDGES;
       e += nb * blockDim.x) {
    int d = dst[e];
    if (d >= lo && d < hi) {
      int p = atomicAdd(&cursor[d], 1);
      col[p] = (ushort_t)src[e];
    }
  }
}

__global__ void scan_block_kernel(const int* __restrict__ degi,
                                  int* __restrict__ partial,
                                  int* __restrict__ bsum,
                                  float* __restrict__ invdeg) {
  __shared__ int buf[2][256];
  int i = blockIdx.x * 256 + threadIdx.x;
  int v = (i < N_NODES) ? degi[i] : 0;
  buf[0][threadIdx.x] = v;
  __syncthreads();
  int pi = 0;
  for (int off = 1; off < 256; off <<= 1) {
    int nv = buf[pi][threadIdx.x];
    if (threadIdx.x >= off) nv += buf[pi][threadIdx.x - off];
    buf[pi ^ 1][threadIdx.x] = nv;
    pi ^= 1;
    __syncthreads();
  }
  int incl = buf[pi][threadIdx.x];
  if (i < N_NODES) {
    partial[i] = incl - v;
    invdeg[i] = 1.0f / fmaxf((float)v, 1.0f);
  }
  if (threadIdx.x == 255) bsum[blockIdx.x] = incl;
}

__global__ void scan_add_fused_kernel(const int* __restrict__ partial,
                                      const int* __restrict__ bsum,
                                      int* __restrict__ rowptr,
                                      int* __restrict__ cursor, int nb) {
  __shared__ int buf[2][256];
  __shared__ int sx[256];
  int t = threadIdx.x;
  int v = (t < nb) ? bsum[t] : 0;
  buf[0][t] = v;
  __syncthreads();
  int pi = 0;
  for (int off = 1; off < 256; off <<= 1) {
    int nv = buf[pi][t];
    if (t >= off) nv += buf[pi][t - off];
    buf[pi ^ 1][t] = nv;
    pi ^= 1;
    __syncthreads();
  }
  sx[t] = buf[pi][t] - v;
  __syncthreads();
  int add = sx[blockIdx.x];
  int i = blockIdx.x * 256 + t;
  if (i < N_NODES) {
    int r = partial[i] + add;
    rowptr[i] = r;
    cursor[i] = r;
  } else if (i == N_NODES) {
    rowptr[N_NODES] = N_EDGES;
  }
}

// ================================================================ prep + hist (one launch)
#define WP0 (128 * 96)
#define WP1 (128 * 256)
__global__ void prep_hist_kernel(const float* __restrict__ Wl0,
                                 const float* __restrict__ Wr0,
                                 const float* __restrict__ Wl,
                                 const float* __restrict__ Wr,
                                 const float* __restrict__ x,
                                 const int* __restrict__ dst,
                                 ushort_t* __restrict__ WT0,
                                 ushort_t* __restrict__ WT1,
                                 ushort_t* __restrict__ WT2,
                                 uint_t* __restrict__ xb,
                                 float* __restrict__ stats,
                                 int* __restrict__ degi, int prep_blocks) {
  if ((int)blockIdx.x >= prep_blocks) {
    const int nb = gridDim.x - prep_blocks;
    const int blk = blockIdx.x - prep_blocks;
    for (int e = blk * blockDim.x + threadIdx.x; e < N_EDGES;
         e += nb * blockDim.x)
      atomicAdd(&degi[dst[e]], 1);
    return;
  }
  int idx = blockIdx.x * blockDim.x + threadIdx.x;
  if (idx < 768) stats[idx] = 0.f;
  if (idx < WP0) {
    int c = idx / 96, k = idx - c * 96;
    float v = 0.f;
    if (k < 38) v = Wl0[k * 128 + c];
    else if (k < 76) v = Wr0[(k - 38) * 128 + c];
    WT0[(k >> 5) * 4096 + c * 32 + (k & 31)] = f2bf(v);
  } else if (idx < WP0 + 2 * WP1) {
    int i2 = idx - WP0;
    int layer = i2 / WP1;
    int j = i2 - layer * WP1;
    int c = j / 256, k = j - c * 256;
    const float* L = Wl + layer * 16384;
    const float* R = Wr + layer * 16384;
    float v = (k < 128) ? L[k * 128 + c] : R[(k - 128) * 128 + c];
    ushort_t* W = layer ? WT2 : WT1;
    W[(k >> 5) * 4096 + c * 32 + (k & 31)] = f2bf(v);
  } else if (idx < WP0 + 2 * WP1 + N_NODES * 20) {
    int j = idx - (WP0 + 2 * WP1);
    int row = j / 20, c2 = (j - row * 20) * 2;
    float v0 = (c2 < 38) ? x[row * 38 + c2] : 0.f;
    float v1 = (c2 + 1 < 38) ? x[row * 38 + c2 + 1] : 0.f;
    xb[j] = pack2(v0, v1);
  }
}

// ================================================================ layer-0 fused
// Gather: 2 nodes/wave, lanes 0..18 own col-pairs, 8-deep unroll
// (8 outstanding uint loads/lane — same MLP medicine as gemm_fused R17).
__global__ __launch_bounds__(256, 6) void gemm0_fused_kernel(
    const uint_t* __restrict__ xb, const int* __restrict__ rowptr,
    const ushort_t* __restrict__ col, const float* __restrict__ invdeg,
    const ushort_t* __restrict__ WT, ushort_t* __restrict__ P,
    uchar_t* __restrict__ Hq, float* __restrict__ stats) {
  __shared__ __align__(16) uint_t aggA[64 * 52];  // 64 rows x 96 bf16 + pad
  __shared__ __align__(16) ushort_t sB[128 * 40];
  const int tid = threadIdx.x;
  const int row0 = blockIdx.x * 64;
  const int w = tid >> 6;
  const int l = tid & 63;

  // ---- gather phase: 2 nodes per wave (32 lanes each), lanes 0..18 active
  {
    int half = l >> 5;
    int j = l & 31;
    for (int pass = 0; pass < 8; pass++) {
      int r = w * 16 + pass * 2 + half;
      int node = row0 + r;
      if (j < 19) {
        uint_t o = 0;
        if (node < N_NODES) {
          int beg = rowptr[node], end = rowptr[node + 1];
          float a0 = 0.f, a1 = 0.f;
          int e = beg;
          for (; e + 7 < end; e += 8) {
            uint_t u[8];
#pragma unroll
            for (int q8 = 0; q8 < 8; q8++)
              u[q8] = xb[(size_t)col[e + q8] * 20 + j];
#pragma unroll
            for (int q8 = 0; q8 < 8; q8++) {
              a0 += bf_lo(u[q8]);
              a1 += bf_hi(u[q8]);
            }
          }
          for (; e + 3 < end; e += 4) {
            uint_t u0 = xb[(size_t)col[e] * 20 + j];
            uint_t u1 = xb[(size_t)col[e + 1] * 20 + j];
            uint_t u2 = xb[(size_t)col[e + 2] * 20 + j];
            uint_t u3 = xb[(size_t)col[e + 3] * 20 + j];
            a0 += (bf_lo(u0) + bf_lo(u1)) + (bf_lo(u2) + bf_lo(u3));
            a1 += (bf_hi(u0) + bf_hi(u1)) + (bf_hi(u2) + bf_hi(u3));
          }
          for (; e < end; e++) {
            uint_t u = xb[(size_t)col[e] * 20 + j];
            a0 += bf_lo(u);
            a1 += bf_hi(u);
          }
          float inv = invdeg[node];
          o = pack2(a0 * inv, a1 * inv);
        }
        aggA[r * 52 + j] = o;
      }
    }
  }
  // ---- self + zero fill: uints 19..47 of each row
  for (int idx = tid; idx < 64 * 29; idx += 256) {
    int r = idx / 29;
    int j2 = idx - r * 29 + 19;
    int node = row0 + r;
    uint_t v = 0;
    if (node < N_NODES && j2 < 38) v = xb[(size_t)node * 20 + (j2 - 19)];
    aggA[r * 52 + j2] = v;
  }

  // ---- K loop (Kc = 96)
  const int m = l & 15;
  const int quad = l >> 4;
  f32x4 acc[8];
#pragma unroll
  for (int ct = 0; ct < 8; ct++) acc[ct] = (f32x4){0.f, 0.f, 0.f, 0.f};

  for (int kk = 0; kk < 96; kk += 32) {
    __syncthreads();
    {
      const uint4* wp = (const uint4*)(WT + (kk >> 5) * 4096);
      uint4 v0 = wp[tid];
      uint4 v1 = wp[tid + 256];
      *((uint4*)&sB[(tid >> 2) * 40 + (tid & 3) * 8]) = v0;
      int t2 = tid + 256;
      *((uint4*)&sB[(t2 >> 2) * 40 + (t2 & 3) * 8]) = v1;
    }
    __syncthreads();
    bf16x8 a = *(const bf16x8*)((const ushort_t*)aggA + (w * 16 + m) * 104 +
                                kk + quad * 8);
#pragma unroll
    for (int ct = 0; ct < 8; ct++) {
      bf16x8 b = *(const bf16x8*)&sB[(ct * 16 + m) * 40 + quad * 8];
      acc[ct] = __builtin_amdgcn_mfma_f32_16x16x32_bf16(a, b, acc[ct], 0, 0, 0);
    }
  }

#pragma unroll
  for (int ct = 0; ct < 8; ct++) {
#pragma unroll
    for (int v = 0; v < 4; v++) {
      int row = row0 + w * 16 + quad * 4 + v;
      if (row < N_NODES) {
        P[(size_t)row * 128 + ct * 16 + m] = f2bf(acc[ct][v]);
        Hq[(size_t)row * 128 + ct * 16 + m] = f2fp8(acc[ct][v]);
      }
    }
  }

  float* red = (float*)sB;
  __syncthreads();
#pragma unroll
  for (int ct = 0; ct < 8; ct++) {
    float s = 0.f, q = 0.f;
#pragma unroll
    for (int v = 0; v < 4; v++) {
      s += acc[ct][v];
      q += acc[ct][v] * acc[ct][v];
    }
    float t;
    t = __shfl_xor(s, 16); s += t;
    t = __shfl_xor(s, 32); s += t;
    t = __shfl_xor(q, 16); q += t;
    t = __shfl_xor(q, 32); q += t;
    if (l < 16) {
      red[w * 256 + ct * 16 + l] = s;
      red[w * 256 + 128 + ct * 16 + l] = q;
    }
  }
  __syncthreads();
  if (tid < 128) {
    float s = 0.f, q = 0.f;
#pragma unroll
    for (int wv = 0; wv < 4; wv++) {
      s += red[wv * 256 + tid];
      q += red[wv * 256 + 128 + tid];
    }
    atomicAdd(&stats[tid], s);
    atomicAdd(&stats[128 + tid], q);
  }
}

// ================================================================ fused layer kernel
// fp8 gather with 8-deep unroll (8 outstanding uint2 loads/lane).
__global__ __launch_bounds__(256, 4) void gemm_fused_kernel(
    const ushort_t* __restrict__ Pin, const uchar_t* __restrict__ Hin,
    const float* __restrict__ stats_prev,
    const float* __restrict__ gamma, const float* __restrict__ beta,
    const int* __restrict__ rowptr, const ushort_t* __restrict__ col,
    const float* __restrict__ invdeg, const ushort_t* __restrict__ WT,
    ushort_t* __restrict__ Pout, uchar_t* __restrict__ Hout,
    float* __restrict__ stats_out) {
  __shared__ __align__(16) uint_t aggu[64 * 68];
  __shared__ __align__(16) ushort_t sA[64 * 40];
  __shared__ __align__(16) ushort_t sB[128 * 40];
  __shared__ float ssc[256];
  const int tid = threadIdx.x;
  const int row0 = blockIdx.x * 64;

  if (tid < 128) {
    const float invN = 1.0f / (float)N_NODES;
    float mean = stats_prev[tid] * invN;
    float var = stats_prev[128 + tid] * invN - mean * mean;
    float scale = gamma[tid] * rsqrtf(var + BN_EPS);
    ssc[tid] = scale;
    ssc[128 + tid] = beta[tid] - mean * scale;
  }
  __syncthreads();

  const int w = tid >> 6;
  const int g2 = (tid >> 4) & 3;
  const int h = tid & 15;
  const uint2* Hu = (const uint2*)Hin;  // row stride 16 uint2 (128 B)
  {
    int c0 = h * 8;
    float s[8], b[8];
#pragma unroll
    for (int j = 0; j < 8; j++) {
      s[j] = ssc[c0 + j];
      b[j] = ssc[128 + c0 + j];
    }
    for (int pass = 0; pass < 4; pass++) {
      int r = w * 16 + pass * 4 + g2;
      int node = row0 + r;
      uint4 o = make_uint4(0, 0, 0, 0);
      if (node < N_NODES) {
        int beg = rowptr[node], end = rowptr[node + 1];
        float a[8];
#pragma unroll
        for (int j = 0; j < 8; j++) a[j] = 0.f;
        int e = beg;
        for (; e + 7 < end; e += 8) {
          uint2 u[8];
#pragma unroll
          for (int q8 = 0; q8 < 8; q8++)
            u[q8] = Hu[(size_t)col[e + q8] * 16 + h];
#pragma unroll
          for (int q8 = 0; q8 < 8; q8++) {
            vf2 f01 = __builtin_amdgcn_cvt_pk_f32_fp8((int)u[q8].x, false);
            vf2 f23 = __builtin_amdgcn_cvt_pk_f32_fp8((int)u[q8].x, true);
            vf2 f45 = __builtin_amdgcn_cvt_pk_f32_fp8((int)u[q8].y, false);
            vf2 f67 = __builtin_amdgcn_cvt_pk_f32_fp8((int)u[q8].y, true);
            a[0] += fmaxf(f01[0] * s[0] + b[0], 0.f);
            a[1] += fmaxf(f01[1] * s[1] + b[1], 0.f);
            a[2] += fmaxf(f23[0] * s[2] + b[2], 0.f);
            a[3] += fmaxf(f23[1] * s[3] + b[3], 0.f);
            a[4] += fmaxf(f45[0] * s[4] + b[4], 0.f);
            a[5] += fmaxf(f45[1] * s[5] + b[5], 0.f);
            a[6] += fmaxf(f67[0] * s[6] + b[6], 0.f);
            a[7] += fmaxf(f67[1] * s[7] + b[7], 0.f);
          }
        }
        for (; e + 3 < end; e += 4) {
          uint2 u[4];
#pragma unroll
          for (int q4 = 0; q4 < 4; q4++)
            u[q4] = Hu[(size_t)col[e + q4] * 16 + h];
#pragma unroll
          for (int q4 = 0; q4 < 4; q4++) {
            vf2 f01 = __builtin_amdgcn_cvt_pk_f32_fp8((int)u[q4].x, false);
            vf2 f23 = __builtin_amdgcn_cvt_pk_f32_fp8((int)u[q4].x, true);
            vf2 f45 = __builtin_amdgcn_cvt_pk_f32_fp8((int)u[q4].y, false);
            vf2 f67 = __builtin_amdgcn_cvt_pk_f32_fp8((int)u[q4].y, true);
            a[0] += fmaxf(f01[0] * s[0] + b[0], 0.f);
            a[1] += fmaxf(f01[1] * s[1] + b[1], 0.f);
            a[2] += fmaxf(f23[0] * s[2] + b[2], 0.f);
            a[3] += fmaxf(f23[1] * s[3] + b[3], 0.f);
            a[4] += fmaxf(f45[0] * s[4] + b[4], 0.f);
            a[5] += fmaxf(f45[1] * s[5] + b[5], 0.f);
            a[6] += fmaxf(f67[0] * s[6] + b[6], 0.f);
            a[7] += fmaxf(f67[1] * s[7] + b[7], 0.f);
          }
        }
        for (; e < end; e++) {
          uint2 u = Hu[(size_t)col[e] * 16 + h];
          vf2 f01 = __builtin_amdgcn_cvt_pk_f32_fp8((int)u.x, false);
          vf2 f23 = __builtin_amdgcn_cvt_pk_f32_fp8((int)u.x, true);
          vf2 f45 = __builtin_amdgcn_cvt_pk_f32_fp8((int)u.y, false);
          vf2 f67 = __builtin_amdgcn_cvt_pk_f32_fp8((int)u.y, true);
          a[0] += fmaxf(f01[0] * s[0] + b[0], 0.f);
          a[1] += fmaxf(f01[1] * s[1] + b[1], 0.f);
          a[2] += fmaxf(f23[0] * s[2] + b[2], 0.f);
          a[3] += fmaxf(f23[1] * s[3] + b[3], 0.f);
          a[4] += fmaxf(f45[0] * s[4] + b[4], 0.f);
          a[5] += fmaxf(f45[1] * s[5] + b[5], 0.f);
          a[6] += fmaxf(f67[0] * s[6] + b[6], 0.f);
          a[7] += fmaxf(f67[1] * s[7] + b[7], 0.f);
        }
        float inv = invdeg[node];
        o.x = pack2(a[0] * inv, a[1] * inv);
        o.y = pack2(a[2] * inv, a[3] * inv);
        o.z = pack2(a[4] * inv, a[5] * inv);
        o.w = pack2(a[6] * inv, a[7] * inv);
      }
      *((uint4*)&aggu[r * 68 + h * 4]) = o;
    }
  }
  __syncthreads();

  const int l = tid & 63;
  const int m = l & 15;
  const int quad = l >> 4;
  f32x4 acc[8];
#pragma unroll
  for (int ct = 0; ct < 8; ct++) acc[ct] = (f32x4){0.f, 0.f, 0.f, 0.f};

  for (int kk = 0; kk < 256; kk += 32) {
    __syncthreads();
    {
      const uint4* wp = (const uint4*)(WT + (kk >> 5) * 4096);
      uint4 v0 = wp[tid];
      uint4 v1 = wp[tid + 256];
      *((uint4*)&sB[(tid >> 2) * 40 + (tid & 3) * 8]) = v0;
      int t2 = tid + 256;
      *((uint4*)&sB[(t2 >> 2) * 40 + (t2 & 3) * 8]) = v1;
    }
    if (kk >= 128) {
      int r = tid >> 2, c = tid & 3;
      int row = row0 + r;
      uint4 v = make_uint4(0, 0, 0, 0);
      if (row < N_NODES) {
        int pcol = kk - 128 + c * 8;
        uint4 u = *(const uint4*)(Pin + (size_t)row * 128 + pcol);
        uint_t in[4] = {u.x, u.y, u.z, u.w};
        uint_t ov[4];
#pragma unroll
        for (int p = 0; p < 4; p++) {
          int cc = pcol + 2 * p;
          float f0 = fmaxf(bf_lo(in[p]) * ssc[cc] + ssc[128 + cc], 0.f);
          float f1 = fmaxf(bf_hi(in[p]) * ssc[cc + 1] + ssc[128 + cc + 1], 0.f);
          ov[p] = pack2(f0, f1);
        }
        v = make_uint4(ov[0], ov[1], ov[2], ov[3]);
      }
      *((uint4*)&sA[r * 40 + c * 8]) = v;
    }
    __syncthreads();
    bf16x8 a;
    if (kk < 128)
      a = *(const bf16x8*)((const ushort_t*)aggu + (w * 16 + m) * 136 + kk + quad * 8);
    else
      a = *(const bf16x8*)&sA[(w * 16 + m) * 40 + quad * 8];
#pragma unroll
    for (int ct = 0; ct < 8; ct++) {
      bf16x8 bb = *(const bf16x8*)&sB[(ct * 16 + m) * 40 + quad * 8];
      acc[ct] = __builtin_amdgcn_mfma_f32_16x16x32_bf16(a, bb, acc[ct], 0, 0, 0);
    }
  }

#pragma unroll
  for (int ct = 0; ct < 8; ct++) {
#pragma unroll
    for (int v = 0; v < 4; v++) {
      int row = row0 + w * 16 + quad * 4 + v;
      if (row < N_NODES) {
        Pout[(size_t)row * 128 + ct * 16 + m] = f2bf(acc[ct][v]);
        Hout[(size_t)row * 128 + ct * 16 + m] = f2fp8(acc[ct][v]);
      }
    }
  }

  float* red = (float*)sA;
  __syncthreads();
#pragma unroll
  for (int ct = 0; ct < 8; ct++) {
    float ss = 0.f, q = 0.f;
#pragma unroll
    for (int v = 0; v < 4; v++) {
      ss += acc[ct][v];
      q += acc[ct][v] * acc[ct][v];
    }
    float t;
    t = __shfl_xor(ss, 16); ss += t;
    t = __shfl_xor(ss, 32); ss += t;
    t = __shfl_xor(q, 16); q += t;
    t = __shfl_xor(q, 32); q += t;
    if (l < 16) {
      red[w * 256 + ct * 16 + l] = ss;
      red[w * 256 + 128 + ct * 16 + l] = q;
    }
  }
  __syncthreads();
  if (tid < 128) {
    float ss = 0.f, q = 0.f;
#pragma unroll
    for (int wv = 0; wv < 4; wv++) {
      ss += red[wv * 256 + tid];
      q += red[wv * 256 + 128 + tid];
    }
    atomicAdd(&stats_out[tid], ss);
    atomicAdd(&stats_out[128 + tid], q);
  }
}

// ================================================================ pool + readout
__global__ __launch_bounds__(128) void pool_readout_kernel(
    const ushort_t* __restrict__ P, const float* __restrict__ stats,
    const float* __restrict__ gamma, const float* __restrict__ beta,
    const int* __restrict__ batch, const float* __restrict__ rW1,
    const float* __restrict__ rb1, const float* __restrict__ rW2,
    const float* __restrict__ rb2, float* __restrict__ out) {
  int g = blockIdx.x;
  int t = threadIdx.x;
  int lo = 0, hi = N_NODES;
  while (lo < hi) { int mid = (lo + hi) >> 1; if (batch[mid] < g) lo = mid + 1; else hi = mid; }
  int gs = lo;
  hi = N_NODES;
  while (lo < hi) { int mid = (lo + hi) >> 1; if (batch[mid] < g + 1) lo = mid + 1; else hi = mid; }
  int ge = lo;
  const float invN = 1.0f / (float)N_NODES;
  float mean = stats[t] * invN;
  float var = stats[128 + t] * invN - mean * mean;
  float s = gamma[t] * rsqrtf(var + BN_EPS);
  float b = beta[t] - mean * s;
  float acc = 0.f;
  const ushort_t* pr = P + (size_t)gs * 128 + t;
  for (int r = gs; r < ge; r++, pr += 128)
    acc += fmaxf(__uint_as_float(((uint_t)*pr) << 16) * s + b, 0.f);
  __shared__ float pl[128];
  pl[t] = acc / fmaxf((float)(ge - gs), 1.f);
  __syncthreads();
  if (t < 64) {
    float h1 = rb1[t];
    for (int k = 0; k < 128; k++) h1 += pl[k] * rW1[k * 64 + t];
    h1 = fmaxf(h1, 0.f) * rW2[t];
#pragma unroll
    for (int off = 32; off > 0; off >>= 1) h1 += __shfl_down(h1, off);
    if (t == 0) out[g] = h1 + rb2[0];
  }
}

// ================================================================ launch
extern "C" void kernel_launch(void* const* d_in, const int* in_sizes, int n_in,
                              void* d_out, int out_size, void* d_ws, size_t ws_size,
                              hipStream_t stream) {
  const float* x     = (const float*)d_in[0];
  const int*   ei    = (const int*)d_in[1];
  const int*   src   = ei;
  const int*   dst   = ei + N_EDGES;
  const int*   batch = (const int*)d_in[2];
  const float* Wl0   = (const float*)d_in[3];
  const float* Wr0   = (const float*)d_in[4];
  const float* Wl    = (const float*)d_in[6];
  const float* Wr    = (const float*)d_in[7];
  const float* gamma = (const float*)d_in[9];
  const float* beta  = (const float*)d_in[10];
  const float* rW1   = (const float*)d_in[11];
  const float* rb1   = (const float*)d_in[12];
  const float* rW2   = (const float*)d_in[13];
  const float* rb2   = (const float*)d_in[14];
  float* out = (float*)d_out;

  char* ws = (char*)d_ws;
  size_t off = 0;
  auto alloc = [&](size_t bytes) -> void* {
    void* p = ws + off;
    off = (off + bytes + 255) & ~(size_t)255;
    return p;
  };
  uint_t*   xb    = (uint_t*)alloc((size_t)N_NODES * 20 * 4);
  ushort_t* Pa    = (ushort_t*)alloc((size_t)N_NODES * 128 * 2);
  ushort_t* Pb    = (ushort_t*)alloc((size_t)N_NODES * 128 * 2);
  uchar_t*  Ha    = (uchar_t*)alloc((size_t)N_NODES * 128);
  uchar_t*  Hb    = (uchar_t*)alloc((size_t)N_NODES * 128);
  ushort_t* WT0   = (ushort_t*)alloc((size_t)128 * 96 * 2);
  ushort_t* WT1   = (ushort_t*)alloc((size_t)128 * 256 * 2);
  ushort_t* WT2   = (ushort_t*)alloc((size_t)128 * 256 * 2);
  float* invdeg = (float*)alloc((size_t)N_NODES * 4);
  int*   degi   = (int*)alloc((size_t)N_NODES * 4);
  int*   rowptr = (int*)alloc((size_t)(N_NODES + 1) * 4);
  int*   cursor = (int*)alloc((size_t)N_NODES * 4);
  ushort_t* colidx = (ushort_t*)alloc((size_t)N_EDGES * 2);
  int*   partial= (int*)alloc((size_t)N_NODES * 4);
  int*   bsum   = (int*)alloc(256 * 4);
  float* stats  = (float*)alloc(768 * 4);  // 3 layers x {sum[128],sumsq[128]}

  const int NB_SCAN = (N_NODES + 255) / 256;  // 196
  const int gemm_blocks = (N_NODES + 63) / 64;
  const int PREP_TOTAL = WP0 + 2 * WP1 + N_NODES * 20;
  const int PREP_BLOCKS = (PREP_TOTAL + 255) / 256;
  const int HIST_BLOCKS = 512;

  // ---- prep (weights/xb/stats) + histogram in one launch
  hipMemsetAsync(degi, 0, (size_t)N_NODES * 4, stream);
  prep_hist_kernel<<<PREP_BLOCKS + HIST_BLOCKS, 256, 0, stream>>>(
      Wl0, Wr0, Wl, Wr, x, dst, WT0, WT1, WT2, xb, stats, degi, PREP_BLOCKS);

  // ---- CSR build
  scan_block_kernel<<<NB_SCAN, 256, 0, stream>>>(degi, partial, bsum, invdeg);
  scan_add_fused_kernel<<<NB_SCAN + 1, 256, 0, stream>>>(partial, bsum, rowptr,
                                                         cursor, NB_SCAN);
  fill_sharded_kernel<<<2048, 256, 0, stream>>>(src, dst, cursor, colidx);

  // ---- layer 0 (fused gather + GEMM) -> Pa (bf16) + Ha (fp8)
  gemm0_fused_kernel<<<gemm_blocks, 256, 0, stream>>>(xb, rowptr, colidx, invdeg,
                                                      WT0, Pa, Ha, stats);

  // ---- layer 1: gather Ha (fp8), self Pa -> Pb + Hb
  gemm_fused_kernel<<<gemm_blocks, 256, 0, stream>>>(
      Pa, Ha, stats, gamma, beta, rowptr, colidx, invdeg, WT1, Pb, Hb,
      stats + 256);

  // ---- layer 2: gather Hb (fp8), self Pb -> Pa (+ Ha dummy)
  gemm_fused_kernel<<<gemm_blocks, 256, 0, stream>>>(
      Pb, Hb, stats + 256, gamma + 128, beta + 128, rowptr, colidx, invdeg,
      WT2, Pa, Ha, stats + 512);

  // ---- fused global mean pool (final BN inline) + readout
  pool_readout_kernel<<<N_GRAPHS, 128, 0, stream>>>(
      Pa, stats + 512, gamma + 256, beta + 256, batch, rW1, rb1, rW2, rb2, out);
}